// Round 5
// baseline (1376.974 us; speedup 1.0000x reference)
//
#include <hip/hip_runtime.h>

// GCNConv: out = A_hat @ x @ W + b, A_hat = D^-1/2 (A + I) D^-1/2
// v10: bucket scatter (v7 2-pass LDS-histogram form, + fused fire-and-forget
// deg atomics) -> standalone bf16 MFMA GEMM (dinv inline from deg) ->
// k_bucket_agg: block-per-bucket aggregation straight from UNSORTED pairs
// into a 64x128 f32 LDS accumulator (16-lane groups gather h[src] rows,
// LDS float atomicAdd into row dl), streaming nt out stores.
// Deletes v7/v8's per-bucket LDS counting sort + sorted-list writeback +
// per-node gather lists (~70us), and v9's latency-bound direct CSR.
// (Round-4 resubmit: round-3 bench died on container infra, kernel unrun.)

#define SCAN_T 256
#define SCAN_E 1024
#define WPB 4
#define CAP 1536      // bucket capacity (mean 1024, +16 sigma)
#define SC_T 8192     // edges per scatter block -> 196 blocks at E=1.6M

typedef __attribute__((ext_vector_type(8))) short short8;
typedef __attribute__((ext_vector_type(4))) float f32x4;

__device__ __forceinline__ unsigned short f2bf(float f) {
  unsigned int u = __float_as_uint(f);
  u += 0x7FFFu + ((u >> 16) & 1u);   // RNE
  return (unsigned short)(u >> 16);
}
__device__ __forceinline__ float bf_lo(unsigned int u) { return __uint_as_float(u << 16); }
__device__ __forceinline__ float bf_hi(unsigned int u) { return __uint_as_float(u & 0xFFFF0000u); }

// ======================= v10 primary path =======================

__global__ void k_zero(int* __restrict__ p, int m) {
  int i = blockIdx.x * blockDim.x + threadIdx.x;
  if (i < m) p[i] = 0;
}

// Bucket-scatter: pairs[b*CAP + slot] = (dst&63)<<17 | src.
// Pass 1 also counts per-node in-degree (fire-and-forget global atomics —
// no return value, so they pipeline; unlike v9's returning atomics).
__global__ void __launch_bounds__(512) k_scatter(
    const int* __restrict__ ei, int* __restrict__ deg, int* __restrict__ bcursor,
    int* __restrict__ pairs, int E, int B) {
  __shared__ int hist[2048];
  int t = threadIdx.x;
  for (int b = t; b < B; b += 512) hist[b] = 0;
  __syncthreads();
  int e0 = blockIdx.x * SC_T;
  int eend = min(e0 + SC_T, E);
  for (int e = e0 + t * 4; e < eend; e += 2048) {
    if (e + 3 < eend) {
      int4 d = *(const int4*)(ei + E + e);
      atomicAdd(&hist[((unsigned)d.x) >> 6], 1);
      atomicAdd(&hist[((unsigned)d.y) >> 6], 1);
      atomicAdd(&hist[((unsigned)d.z) >> 6], 1);
      atomicAdd(&hist[((unsigned)d.w) >> 6], 1);
      atomicAdd(&deg[d.x], 1);
      atomicAdd(&deg[d.y], 1);
      atomicAdd(&deg[d.z], 1);
      atomicAdd(&deg[d.w], 1);
    } else {
      for (int q = e; q < eend; ++q) {
        int dst = ei[E + q];
        atomicAdd(&hist[((unsigned)dst) >> 6], 1);
        atomicAdd(&deg[dst], 1);
      }
    }
  }
  __syncthreads();
  for (int b = t; b < B; b += 512) {
    int c = hist[b];
    hist[b] = c ? atomicAdd(&bcursor[b], c) : 0;  // base within bucket
  }
  __syncthreads();
  for (int e = e0 + t * 4; e < eend; e += 2048) {
    if (e + 3 < eend) {
      int4 s = *(const int4*)(ei + e);
      int4 d = *(const int4*)(ei + E + e);
      int b0 = ((unsigned)d.x) >> 6; int p0 = atomicAdd(&hist[b0], 1);
      if (p0 < CAP) pairs[(size_t)b0 * CAP + p0] = ((d.x & 63) << 17) | s.x;
      int b1 = ((unsigned)d.y) >> 6; int p1 = atomicAdd(&hist[b1], 1);
      if (p1 < CAP) pairs[(size_t)b1 * CAP + p1] = ((d.y & 63) << 17) | s.y;
      int b2 = ((unsigned)d.z) >> 6; int p2 = atomicAdd(&hist[b2], 1);
      if (p2 < CAP) pairs[(size_t)b2 * CAP + p2] = ((d.z & 63) << 17) | s.z;
      int b3 = ((unsigned)d.w) >> 6; int p3 = atomicAdd(&hist[b3], 1);
      if (p3 < CAP) pairs[(size_t)b3 * CAP + p3] = ((d.w & 63) << 17) | s.w;
    } else {
      for (int q = e; q < eend; ++q) {
        int dst = ei[E + q], src = ei[q];
        int b0 = ((unsigned)dst) >> 6; int p0 = atomicAdd(&hist[b0], 1);
        if (p0 < CAP) pairs[(size_t)b0 * CAP + p0] = ((dst & 63) << 17) | src;
      }
    }
  }
}

// bf16 MFMA GEMM: h = dinv * (x @ W), dinv = rsqrt(deg+1) inline.
__global__ void __launch_bounds__(256) k_gemm_h2(
    const float* __restrict__ x, const float* __restrict__ W,
    const int* __restrict__ cnt, unsigned short* __restrict__ h, int n) {
  __shared__ alignas(16) unsigned short Wt[128][136];
  int t = threadIdx.x;
#pragma unroll
  for (int p = 0; p < 16; ++p) {
    int task = p * 256 + t;
    int kg = task >> 7, nn = task & 127;
    float w0 = W[(kg * 4 + 0) * 128 + nn];
    float w1 = W[(kg * 4 + 1) * 128 + nn];
    float w2 = W[(kg * 4 + 2) * 128 + nn];
    float w3 = W[(kg * 4 + 3) * 128 + nn];
    ushort4 u;
    u.x = f2bf(w0); u.y = f2bf(w1); u.z = f2bf(w2); u.w = f2bf(w3);
    *(ushort4*)&Wt[nn][kg * 4] = u;
  }
  __syncthreads();
  int w = t >> 6, lane = t & 63;
  int q = lane >> 4, m = lane & 15;
  int r0 = blockIdx.x * 64 + w * 16;
  f32x4 acc[8];
#pragma unroll
  for (int nt = 0; nt < 8; ++nt) acc[nt] = (f32x4){0.f, 0.f, 0.f, 0.f};
  float dscale[4];
#pragma unroll
  for (int rg = 0; rg < 4; ++rg) {
    int r = r0 + q * 4 + rg;
    dscale[rg] = rsqrtf((float)cnt[r < n ? r : n - 1] + 1.0f);
  }
#pragma unroll
  for (int ks = 0; ks < 4; ++ks) {
    int row = r0 + m;
    row = row < n ? row : n - 1;
    const float* xp = x + (size_t)row * 128 + ks * 32 + q * 8;
    float4 a0 = *(const float4*)xp;
    float4 a1 = *(const float4*)(xp + 4);
    short8 af;
    af[0] = (short)f2bf(a0.x); af[1] = (short)f2bf(a0.y);
    af[2] = (short)f2bf(a0.z); af[3] = (short)f2bf(a0.w);
    af[4] = (short)f2bf(a1.x); af[5] = (short)f2bf(a1.y);
    af[6] = (short)f2bf(a1.z); af[7] = (short)f2bf(a1.w);
#pragma unroll
    for (int nt = 0; nt < 8; ++nt) {
      short8 bf = *(const short8*)&Wt[nt * 16 + m][ks * 32 + q * 8];
      acc[nt] = __builtin_amdgcn_mfma_f32_16x16x32_bf16(af, bf, acc[nt], 0, 0, 0);
    }
  }
#pragma unroll
  for (int nt = 0; nt < 8; ++nt)
#pragma unroll
    for (int rg = 0; rg < 4; ++rg) {
      int r = r0 + q * 4 + rg;
      if (r < n) h[(size_t)r * 128 + nt * 16 + m] = f2bf(acc[nt][rg] * dscale[rg]);
    }
}

// Block-per-bucket aggregation from UNSORTED pairs.
// acc[64][132] f32 in LDS (33 KB, +4-pad decorrelates banks across rows).
// 16 groups x 16 lanes; group reads pair word (broadcast), lanes gather the
// 256B h[src] row as uint4, LDS float atomicAdd into acc[dl]. 4-deep unroll
// keeps 16 rows (4 KB) in flight per wave.
__global__ void __launch_bounds__(256) k_bucket_agg(
    const uint4* __restrict__ h4, const int* __restrict__ deg,
    const int* __restrict__ bcursor, const int* __restrict__ pairs,
    const float* __restrict__ bias, float* __restrict__ out, int n) {
  __shared__ float acc[64][132];
  int t = threadIdx.x;
  int b = blockIdx.x;
  int base = b << 6;
  // init acc with the self term h'[node]
#pragma unroll
  for (int p = 0; p < 4; ++p) {
    int task = p * 256 + t;           // 1024 tasks = 64 rows x 16 slots
    int row = task >> 4, sl = task & 15;
    int node = base + row;
    uint4 u = make_uint4(0u, 0u, 0u, 0u);
    if (node < n) u = h4[(size_t)node * 16 + sl];
    float* ap = &acc[row][sl * 8];
    ap[0] = bf_lo(u.x); ap[1] = bf_hi(u.x);
    ap[2] = bf_lo(u.y); ap[3] = bf_hi(u.y);
    ap[4] = bf_lo(u.z); ap[5] = bf_hi(u.z);
    ap[6] = bf_lo(u.w); ap[7] = bf_hi(u.w);
  }
  __syncthreads();
  int cnt = min(bcursor[b], CAP);
  const int* __restrict__ gp = pairs + (size_t)b * CAP;
  int g = t >> 4, ln = t & 15;
  int i = g;
  for (; i + 48 < cnt; i += 64) {
    int p0 = gp[i];
    int p1 = gp[i + 16];
    int p2 = gp[i + 32];
    int p3 = gp[i + 48];
    uint4 u0 = h4[(size_t)(p0 & 0x1FFFF) * 16 + ln];
    uint4 u1 = h4[(size_t)(p1 & 0x1FFFF) * 16 + ln];
    uint4 u2 = h4[(size_t)(p2 & 0x1FFFF) * 16 + ln];
    uint4 u3 = h4[(size_t)(p3 & 0x1FFFF) * 16 + ln];
    {
      float* a = &acc[p0 >> 17][ln * 8];
      atomicAdd(&a[0], bf_lo(u0.x)); atomicAdd(&a[1], bf_hi(u0.x));
      atomicAdd(&a[2], bf_lo(u0.y)); atomicAdd(&a[3], bf_hi(u0.y));
      atomicAdd(&a[4], bf_lo(u0.z)); atomicAdd(&a[5], bf_hi(u0.z));
      atomicAdd(&a[6], bf_lo(u0.w)); atomicAdd(&a[7], bf_hi(u0.w));
    }
    {
      float* a = &acc[p1 >> 17][ln * 8];
      atomicAdd(&a[0], bf_lo(u1.x)); atomicAdd(&a[1], bf_hi(u1.x));
      atomicAdd(&a[2], bf_lo(u1.y)); atomicAdd(&a[3], bf_hi(u1.y));
      atomicAdd(&a[4], bf_lo(u1.z)); atomicAdd(&a[5], bf_hi(u1.z));
      atomicAdd(&a[6], bf_lo(u1.w)); atomicAdd(&a[7], bf_hi(u1.w));
    }
    {
      float* a = &acc[p2 >> 17][ln * 8];
      atomicAdd(&a[0], bf_lo(u2.x)); atomicAdd(&a[1], bf_hi(u2.x));
      atomicAdd(&a[2], bf_lo(u2.y)); atomicAdd(&a[3], bf_hi(u2.y));
      atomicAdd(&a[4], bf_lo(u2.z)); atomicAdd(&a[5], bf_hi(u2.z));
      atomicAdd(&a[6], bf_lo(u2.w)); atomicAdd(&a[7], bf_hi(u2.w));
    }
    {
      float* a = &acc[p3 >> 17][ln * 8];
      atomicAdd(&a[0], bf_lo(u3.x)); atomicAdd(&a[1], bf_hi(u3.x));
      atomicAdd(&a[2], bf_lo(u3.y)); atomicAdd(&a[3], bf_hi(u3.y));
      atomicAdd(&a[4], bf_lo(u3.z)); atomicAdd(&a[5], bf_hi(u3.z));
      atomicAdd(&a[6], bf_lo(u3.w)); atomicAdd(&a[7], bf_hi(u3.w));
    }
  }
  for (; i < cnt; i += 16) {
    int p0 = gp[i];
    uint4 u0 = h4[(size_t)(p0 & 0x1FFFF) * 16 + ln];
    float* a = &acc[p0 >> 17][ln * 8];
    atomicAdd(&a[0], bf_lo(u0.x)); atomicAdd(&a[1], bf_hi(u0.x));
    atomicAdd(&a[2], bf_lo(u0.y)); atomicAdd(&a[3], bf_hi(u0.y));
    atomicAdd(&a[4], bf_lo(u0.z)); atomicAdd(&a[5], bf_hi(u0.z));
    atomicAdd(&a[6], bf_lo(u0.w)); atomicAdd(&a[7], bf_hi(u0.w));
  }
  __syncthreads();
  // writeback: out = dinv * acc + bias (streaming, non-temporal)
#pragma unroll
  for (int p = 0; p < 4; ++p) {
    int task = p * 256 + t;
    int row = task >> 4, sl = task & 15;
    int node = base + row;
    if (node < n) {
      float di = rsqrtf((float)deg[node] + 1.0f);
      const float* ap = &acc[row][sl * 8];
      float4 b0 = ((const float4*)bias)[2 * sl];
      float4 b1 = ((const float4*)bias)[2 * sl + 1];
      f32x4 r0, r1;
      r0[0] = fmaf(ap[0], di, b0.x); r0[1] = fmaf(ap[1], di, b0.y);
      r0[2] = fmaf(ap[2], di, b0.z); r0[3] = fmaf(ap[3], di, b0.w);
      r1[0] = fmaf(ap[4], di, b1.x); r1[1] = fmaf(ap[5], di, b1.y);
      r1[2] = fmaf(ap[6], di, b1.z); r1[3] = fmaf(ap[7], di, b1.w);
      f32x4* op = (f32x4*)(out + (size_t)node * 128 + sl * 8);
      __builtin_nontemporal_store(r0, op);
      __builtin_nontemporal_store(r1, op + 1);
    }
  }
}

// ======================= round-3 CSR fallback =======================

__global__ void k_init(int* __restrict__ cnt, int n) {
  int i = blockIdx.x * blockDim.x + threadIdx.x;
  if (i < n) cnt[i] = 0;
}

__global__ void k_count4(const int* __restrict__ ei, int* __restrict__ cnt, int E) {
  int i = blockIdx.x * blockDim.x + threadIdx.x;
  int e = i * 4;
  if (e + 3 < E) {
    int4 d = *(const int4*)(ei + E + e);
    atomicAdd(&cnt[d.x], 1); atomicAdd(&cnt[d.y], 1);
    atomicAdd(&cnt[d.z], 1); atomicAdd(&cnt[d.w], 1);
  } else {
    for (; e < E; ++e) atomicAdd(&cnt[ei[E + e]], 1);
  }
}

__global__ void k_scan_local(const int* __restrict__ cnt, int* __restrict__ offs,
                             int* __restrict__ bsums, int n) {
  __shared__ int sh[SCAN_T];
  int t = threadIdx.x;
  int base = blockIdx.x * SCAN_E + t * 4;
  int v0 = 0, v1 = 0, v2 = 0, v3 = 0;
  if (base + 0 < n) v0 = cnt[base + 0];
  if (base + 1 < n) v1 = cnt[base + 1];
  if (base + 2 < n) v2 = cnt[base + 2];
  if (base + 3 < n) v3 = cnt[base + 3];
  int sum = v0 + v1 + v2 + v3;
  sh[t] = sum;
  __syncthreads();
  for (int d = 1; d < SCAN_T; d <<= 1) {
    int xv = (t >= d) ? sh[t - d] : 0;
    __syncthreads();
    sh[t] += xv;
    __syncthreads();
  }
  int run = sh[t] - sum;
  if (base + 0 < n) offs[base + 0] = run; run += v0;
  if (base + 1 < n) offs[base + 1] = run; run += v1;
  if (base + 2 < n) offs[base + 2] = run; run += v2;
  if (base + 3 < n) offs[base + 3] = run;
  if (t == SCAN_T - 1) bsums[blockIdx.x] = sh[t];
}

__global__ void k_scan_bsums(int* __restrict__ bsums, int nb) {
  __shared__ int sh[SCAN_T];
  int t = threadIdx.x;
  int v = (t < nb) ? bsums[t] : 0;
  sh[t] = v;
  __syncthreads();
  for (int d = 1; d < SCAN_T; d <<= 1) {
    int xv = (t >= d) ? sh[t - d] : 0;
    __syncthreads();
    sh[t] += xv;
    __syncthreads();
  }
  if (t < nb) bsums[t] = sh[t] - v;
}

__global__ void k_scan_finish(int* __restrict__ offs, const int* __restrict__ bsums,
                              const int* __restrict__ cnt, int* __restrict__ offs2,
                              float* __restrict__ dinv, int n) {
  int i = blockIdx.x * blockDim.x + threadIdx.x;
  if (i < n) {
    int o = offs[i] + bsums[i / SCAN_E];
    offs[i] = o;
    offs2[i] = o;
    dinv[i] = rsqrtf((float)cnt[i] + 1.0f);
  }
}

__global__ void k_fill4(const int* __restrict__ ei, int* __restrict__ offs2,
                        int* __restrict__ csr, int E) {
  int i = blockIdx.x * blockDim.x + threadIdx.x;
  int e = i * 4;
  if (e + 3 < E) {
    int4 s = *(const int4*)(ei + e);
    int4 d = *(const int4*)(ei + E + e);
    csr[atomicAdd(&offs2[d.x], 1)] = s.x;
    csr[atomicAdd(&offs2[d.y], 1)] = s.y;
    csr[atomicAdd(&offs2[d.z], 1)] = s.z;
    csr[atomicAdd(&offs2[d.w], 1)] = s.w;
  } else {
    for (; e < E; ++e) csr[atomicAdd(&offs2[ei[E + e]], 1)] = ei[e];
  }
}

__global__ void __launch_bounds__(256) k_gemm_h(
    const float* __restrict__ x, const float* __restrict__ W,
    const float* __restrict__ dinv, unsigned short* __restrict__ h, int n) {
  __shared__ alignas(16) unsigned short Wt[128][136];
  int t = threadIdx.x;
#pragma unroll
  for (int p = 0; p < 16; ++p) {
    int task = p * 256 + t;
    int kg = task >> 7, nn = task & 127;
    float w0 = W[(kg * 4 + 0) * 128 + nn];
    float w1 = W[(kg * 4 + 1) * 128 + nn];
    float w2 = W[(kg * 4 + 2) * 128 + nn];
    float w3 = W[(kg * 4 + 3) * 128 + nn];
    ushort4 u;
    u.x = f2bf(w0); u.y = f2bf(w1); u.z = f2bf(w2); u.w = f2bf(w3);
    *(ushort4*)&Wt[nn][kg * 4] = u;
  }
  __syncthreads();
  int w = t >> 6, lane = t & 63;
  int q = lane >> 4, m = lane & 15;
  int r0 = blockIdx.x * 64 + w * 16;
  f32x4 acc[8];
#pragma unroll
  for (int nt = 0; nt < 8; ++nt) acc[nt] = (f32x4){0.f, 0.f, 0.f, 0.f};
  float dscale[4];
#pragma unroll
  for (int rg = 0; rg < 4; ++rg) {
    int r = r0 + q * 4 + rg;
    dscale[rg] = dinv[r < n ? r : n - 1];
  }
#pragma unroll
  for (int ks = 0; ks < 4; ++ks) {
    int row = r0 + m;
    row = row < n ? row : n - 1;
    const float* xp = x + (size_t)row * 128 + ks * 32 + q * 8;
    float4 a0 = *(const float4*)xp;
    float4 a1 = *(const float4*)(xp + 4);
    short8 af;
    af[0] = (short)f2bf(a0.x); af[1] = (short)f2bf(a0.y);
    af[2] = (short)f2bf(a0.z); af[3] = (short)f2bf(a0.w);
    af[4] = (short)f2bf(a1.x); af[5] = (short)f2bf(a1.y);
    af[6] = (short)f2bf(a1.z); af[7] = (short)f2bf(a1.w);
#pragma unroll
    for (int nt = 0; nt < 8; ++nt) {
      short8 bf = *(const short8*)&Wt[nt * 16 + m][ks * 32 + q * 8];
      acc[nt] = __builtin_amdgcn_mfma_f32_16x16x32_bf16(af, bf, acc[nt], 0, 0, 0);
    }
  }
#pragma unroll
  for (int nt = 0; nt < 8; ++nt)
#pragma unroll
    for (int rg = 0; rg < 4; ++rg) {
      int r = r0 + q * 4 + rg;
      if (r < n) h[(size_t)r * 128 + nt * 16 + m] = f2bf(acc[nt][rg] * dscale[rg]);
    }
}

__global__ void __launch_bounds__(256) k_agg_bias_csr(
    const unsigned int* __restrict__ h2, const float* __restrict__ dinv,
    const int* __restrict__ offs, const int* __restrict__ cnt,
    const int* __restrict__ csr, const float* __restrict__ bias,
    float* __restrict__ out, int n) {
  int node = blockIdx.x * WPB + (threadIdx.x >> 6);
  int lane = threadIdx.x & 63;
  if (node >= n) return;
  unsigned int sp = h2[(size_t)node * 64 + lane];
  float ax = bf_lo(sp), ay = bf_hi(sp);
  int s = offs[node];
  int end = s + cnt[node];
  for (; s + 8 <= end; s += 8) {
    int i0 = csr[s + 0], i1 = csr[s + 1], i2 = csr[s + 2], i3 = csr[s + 3];
    int i4 = csr[s + 4], i5 = csr[s + 5], i6 = csr[s + 6], i7 = csr[s + 7];
    unsigned int u0 = h2[(size_t)i0 * 64 + lane];
    unsigned int u1 = h2[(size_t)i1 * 64 + lane];
    unsigned int u2 = h2[(size_t)i2 * 64 + lane];
    unsigned int u3 = h2[(size_t)i3 * 64 + lane];
    unsigned int u4 = h2[(size_t)i4 * 64 + lane];
    unsigned int u5 = h2[(size_t)i5 * 64 + lane];
    unsigned int u6 = h2[(size_t)i6 * 64 + lane];
    unsigned int u7 = h2[(size_t)i7 * 64 + lane];
    ax += (bf_lo(u0) + bf_lo(u1)) + (bf_lo(u2) + bf_lo(u3)) +
          (bf_lo(u4) + bf_lo(u5)) + (bf_lo(u6) + bf_lo(u7));
    ay += (bf_hi(u0) + bf_hi(u1)) + (bf_hi(u2) + bf_hi(u3)) +
          (bf_hi(u4) + bf_hi(u5)) + (bf_hi(u6) + bf_hi(u7));
  }
  for (; s < end; ++s) {
    unsigned int u = h2[(size_t)csr[s] * 64 + lane];
    ax += bf_lo(u); ay += bf_hi(u);
  }
  float di = dinv[node];
  float2 bb = ((const float2*)bias)[lane];
  float2 r;
  r.x = fmaf(ax, di, bb.x);
  r.y = fmaf(ay, di, bb.y);
  ((float2*)out)[(size_t)node * 64 + lane] = r;
}

extern "C" void kernel_launch(void* const* d_in, const int* in_sizes, int n_in,
                              void* d_out, int out_size, void* d_ws, size_t ws_size,
                              hipStream_t stream) {
  const float* x = (const float*)d_in[0];
  const int* ei = (const int*)d_in[1];   // harness delivers integers as int32
  const float* Wm = (const float*)d_in[2];
  const float* bias = (const float*)d_in[3];
  float* out = (float*)d_out;

  int N = in_sizes[0] / 128;
  int E = in_sizes[1] / 2;
  int NB = (N + 63) >> 6;

  int nb_n = (N + 255) / 256;
  int nb_e4 = ((E + 3) / 4 + 255) / 256;

  // ---- v10: deg[N] | bcursor[2048] | pairs[NB*CAP] | h[N*128 bf16] ----
  size_t off_bc = ((size_t)N * 4 + 255) & ~(size_t)255;
  size_t off_pairs = off_bc + 8192;
  size_t off_h = (off_pairs + (size_t)NB * CAP * 4 + 255) & ~(size_t)255;
  size_t need10 = off_h + (size_t)N * 256;

  if (ws_size >= need10 && N <= (1 << 17) && NB <= 2048) {
    char* p = (char*)d_ws;
    int* deg = (int*)p;
    int* bcursor = (int*)(p + off_bc);
    int* pairs = (int*)(p + off_pairs);
    unsigned short* h = (unsigned short*)(p + off_h);

    k_zero<<<nb_n, 256, 0, stream>>>(deg, N);
    k_zero<<<8, 256, 0, stream>>>(bcursor, 2048);
    k_scatter<<<(E + SC_T - 1) / SC_T, 512, 0, stream>>>(ei, deg, bcursor, pairs, E, NB);
    k_gemm_h2<<<NB, 256, 0, stream>>>(x, Wm, deg, h, N);
    k_bucket_agg<<<NB, 256, 0, stream>>>(
        (const uint4*)h, deg, bcursor, pairs, bias, out, N);
    return;
  }

  // ---- round-3 CSR fallback ----
  char* p = (char*)d_ws;
  int* cnt = (int*)p;        p += (size_t)N * 4;
  int* offs = (int*)p;       p += (size_t)N * 4;
  int* offs2 = (int*)p;      p += (size_t)N * 4;
  float* dinv = (float*)p;   p += (size_t)N * 4;
  int* bsums = (int*)p;      p += 1024;
  int* csr = (int*)p;        p += (size_t)E * 4;
  unsigned short* h = (unsigned short*)p;

  int nb_scan = (N + SCAN_E - 1) / SCAN_E;

  k_init<<<nb_n, 256, 0, stream>>>(cnt, N);
  k_count4<<<nb_e4, 256, 0, stream>>>(ei, cnt, E);
  k_scan_local<<<nb_scan, SCAN_T, 0, stream>>>(cnt, offs, bsums, N);
  k_scan_bsums<<<1, SCAN_T, 0, stream>>>(bsums, nb_scan);
  k_scan_finish<<<nb_n, 256, 0, stream>>>(offs, bsums, cnt, offs2, dinv, N);
  k_fill4<<<nb_e4, 256, 0, stream>>>(ei, offs2, csr, E);
  k_gemm_h<<<(N + 63) / 64, 256, 0, stream>>>(x, Wm, dinv, h, N);
  k_agg_bias_csr<<<(N + WPB - 1) / WPB, 256, 0, stream>>>(
      (const unsigned int*)h, dinv, offs, cnt, csr, bias, out, N);
}

// Round 6
// 259.464 us; speedup vs baseline: 5.3070x; 5.3070x over previous
//
#include <hip/hip_runtime.h>

// GCNConv: out = A_hat @ x @ W + b, A_hat = D^-1/2 (A + I) D^-1/2
// v11: k_zero -> k_scatter (v7 2-pass LDS-histogram bucket scatter + fused
// fire-and-forget deg atomics) -> k_gemm_h2 (bf16 MFMA, dinv inline from deg)
// -> k_sort_agg: per-bucket LDS counting sort, then IMMEDIATE register-
// accumulate gather-aggregation (v8b pattern: 16-lane groups, uint4 row
// gathers, 8-deep unroll) and streaming nt out stores. No sorted-list
// writeback, no pairs re-read, no onc/dinv arrays, no LDS atomics in agg
// (v10's LDS float atomics serialized catastrophically - refuted).

#define SCAN_T 256
#define SCAN_E 1024
#define WPB 4
#define CAP 1536      // bucket capacity (mean 1024, +16 sigma)
#define SC_T 8192     // edges per scatter block -> 196 blocks at E=1.6M

typedef __attribute__((ext_vector_type(8))) short short8;
typedef __attribute__((ext_vector_type(4))) float f32x4;

__device__ __forceinline__ unsigned short f2bf(float f) {
  unsigned int u = __float_as_uint(f);
  u += 0x7FFFu + ((u >> 16) & 1u);   // RNE
  return (unsigned short)(u >> 16);
}
__device__ __forceinline__ float bf_lo(unsigned int u) { return __uint_as_float(u << 16); }
__device__ __forceinline__ float bf_hi(unsigned int u) { return __uint_as_float(u & 0xFFFF0000u); }

// ======================= v11 primary path =======================

__global__ void k_zero(int* __restrict__ p, int m) {
  int i = blockIdx.x * blockDim.x + threadIdx.x;
  if (i < m) p[i] = 0;
}

// Bucket-scatter: pairs[b*CAP + slot] = (dst&63)<<17 | src.
// Pass 1 also counts per-node in-degree (fire-and-forget global atomics).
__global__ void __launch_bounds__(512) k_scatter(
    const int* __restrict__ ei, int* __restrict__ deg, int* __restrict__ bcursor,
    int* __restrict__ pairs, int E, int B) {
  __shared__ int hist[2048];
  int t = threadIdx.x;
  for (int b = t; b < B; b += 512) hist[b] = 0;
  __syncthreads();
  int e0 = blockIdx.x * SC_T;
  int eend = min(e0 + SC_T, E);
  for (int e = e0 + t * 4; e < eend; e += 2048) {
    if (e + 3 < eend) {
      int4 d = *(const int4*)(ei + E + e);
      atomicAdd(&hist[((unsigned)d.x) >> 6], 1);
      atomicAdd(&hist[((unsigned)d.y) >> 6], 1);
      atomicAdd(&hist[((unsigned)d.z) >> 6], 1);
      atomicAdd(&hist[((unsigned)d.w) >> 6], 1);
      atomicAdd(&deg[d.x], 1);
      atomicAdd(&deg[d.y], 1);
      atomicAdd(&deg[d.z], 1);
      atomicAdd(&deg[d.w], 1);
    } else {
      for (int q = e; q < eend; ++q) {
        int dst = ei[E + q];
        atomicAdd(&hist[((unsigned)dst) >> 6], 1);
        atomicAdd(&deg[dst], 1);
      }
    }
  }
  __syncthreads();
  for (int b = t; b < B; b += 512) {
    int c = hist[b];
    hist[b] = c ? atomicAdd(&bcursor[b], c) : 0;  // base within bucket
  }
  __syncthreads();
  for (int e = e0 + t * 4; e < eend; e += 2048) {
    if (e + 3 < eend) {
      int4 s = *(const int4*)(ei + e);
      int4 d = *(const int4*)(ei + E + e);
      int b0 = ((unsigned)d.x) >> 6; int p0 = atomicAdd(&hist[b0], 1);
      if (p0 < CAP) pairs[(size_t)b0 * CAP + p0] = ((d.x & 63) << 17) | s.x;
      int b1 = ((unsigned)d.y) >> 6; int p1 = atomicAdd(&hist[b1], 1);
      if (p1 < CAP) pairs[(size_t)b1 * CAP + p1] = ((d.y & 63) << 17) | s.y;
      int b2 = ((unsigned)d.z) >> 6; int p2 = atomicAdd(&hist[b2], 1);
      if (p2 < CAP) pairs[(size_t)b2 * CAP + p2] = ((d.z & 63) << 17) | s.z;
      int b3 = ((unsigned)d.w) >> 6; int p3 = atomicAdd(&hist[b3], 1);
      if (p3 < CAP) pairs[(size_t)b3 * CAP + p3] = ((d.w & 63) << 17) | s.w;
    } else {
      for (int q = e; q < eend; ++q) {
        int dst = ei[E + q], src = ei[q];
        int b0 = ((unsigned)dst) >> 6; int p0 = atomicAdd(&hist[b0], 1);
        if (p0 < CAP) pairs[(size_t)b0 * CAP + p0] = ((dst & 63) << 17) | src;
      }
    }
  }
}

// bf16 MFMA GEMM: h = dinv * (x @ W), dinv = rsqrt(deg+1) inline.
__global__ void __launch_bounds__(256) k_gemm_h2(
    const float* __restrict__ x, const float* __restrict__ W,
    const int* __restrict__ cnt, unsigned short* __restrict__ h, int n) {
  __shared__ alignas(16) unsigned short Wt[128][136];
  int t = threadIdx.x;
#pragma unroll
  for (int p = 0; p < 16; ++p) {
    int task = p * 256 + t;
    int kg = task >> 7, nn = task & 127;
    float w0 = W[(kg * 4 + 0) * 128 + nn];
    float w1 = W[(kg * 4 + 1) * 128 + nn];
    float w2 = W[(kg * 4 + 2) * 128 + nn];
    float w3 = W[(kg * 4 + 3) * 128 + nn];
    ushort4 u;
    u.x = f2bf(w0); u.y = f2bf(w1); u.z = f2bf(w2); u.w = f2bf(w3);
    *(ushort4*)&Wt[nn][kg * 4] = u;
  }
  __syncthreads();
  int w = t >> 6, lane = t & 63;
  int q = lane >> 4, m = lane & 15;
  int r0 = blockIdx.x * 64 + w * 16;
  f32x4 acc[8];
#pragma unroll
  for (int nt = 0; nt < 8; ++nt) acc[nt] = (f32x4){0.f, 0.f, 0.f, 0.f};
  float dscale[4];
#pragma unroll
  for (int rg = 0; rg < 4; ++rg) {
    int r = r0 + q * 4 + rg;
    dscale[rg] = rsqrtf((float)cnt[r < n ? r : n - 1] + 1.0f);
  }
#pragma unroll
  for (int ks = 0; ks < 4; ++ks) {
    int row = r0 + m;
    row = row < n ? row : n - 1;
    const float* xp = x + (size_t)row * 128 + ks * 32 + q * 8;
    float4 a0 = *(const float4*)xp;
    float4 a1 = *(const float4*)(xp + 4);
    short8 af;
    af[0] = (short)f2bf(a0.x); af[1] = (short)f2bf(a0.y);
    af[2] = (short)f2bf(a0.z); af[3] = (short)f2bf(a0.w);
    af[4] = (short)f2bf(a1.x); af[5] = (short)f2bf(a1.y);
    af[6] = (short)f2bf(a1.z); af[7] = (short)f2bf(a1.w);
#pragma unroll
    for (int nt = 0; nt < 8; ++nt) {
      short8 bf = *(const short8*)&Wt[nt * 16 + m][ks * 32 + q * 8];
      acc[nt] = __builtin_amdgcn_mfma_f32_16x16x32_bf16(af, bf, acc[nt], 0, 0, 0);
    }
  }
#pragma unroll
  for (int nt = 0; nt < 8; ++nt)
#pragma unroll
    for (int rg = 0; rg < 4; ++rg) {
      int r = r0 + q * 4 + rg;
      if (r < n) h[(size_t)r * 128 + nt * 16 + m] = f2bf(acc[nt][rg] * dscale[rg]);
    }
}

// Fused sort + aggregate. Block b == bucket b == nodes b*64..b*64+63.
// Phase 1: LDS counting sort of the bucket's (dl,src) pairs -> sorted[] src
// lists grouped by dl, with base_[dl]/hist[dl]. Phase 2: 16 groups x 16
// lanes; group g aggregates nodes g+16*rep (rep=0..3) by gathering h[src]
// rows (uint4, 8-deep unroll, register accumulate), then out = dinv*a + bias.
__global__ void __launch_bounds__(256) k_sort_agg(
    const int* __restrict__ pairs, const int* __restrict__ bcursor,
    const uint4* __restrict__ h4, const float* __restrict__ bias,
    float* __restrict__ out, int n) {
  __shared__ int pb[CAP];
  __shared__ int sorted[CAP];
  __shared__ int hist[64], base_[64], cur[64];
  int t = threadIdx.x;
  int b = blockIdx.x;
  if (t < 64) { hist[t] = 0; cur[t] = 0; }
  __syncthreads();
  int cnt = min(bcursor[b], CAP);
  const int* __restrict__ gp = pairs + (size_t)b * CAP;
  for (int i = t; i < cnt; i += 256) {
    int p = gp[i];
    pb[i] = p;
    atomicAdd(&hist[p >> 17], 1);
  }
  __syncthreads();
  if (t < 64) {  // wave 0: inclusive scan via shuffles
    int v = hist[t];
    int incl = v;
#pragma unroll
    for (int d = 1; d < 64; d <<= 1) {
      int u = __shfl_up(incl, d, 64);
      if (t >= d) incl += u;
    }
    base_[t] = incl - v;
  }
  __syncthreads();
  for (int i = t; i < cnt; i += 256) {
    int p = pb[i];
    int d = p >> 17;
    int pos = base_[d] + atomicAdd(&cur[d], 1);
    sorted[pos] = p & 0x1FFFF;
  }
  __syncthreads();

  // ---- phase 2: gather-aggregate (v8b register pattern) ----
  int g = t >> 4, ln = t & 15;
  int nbase = b << 6;
#pragma unroll
  for (int rep = 0; rep < 4; ++rep) {
    int row = g + rep * 16;
    int node = nbase + row;
    bool act = node < n;
    uint4 sp = make_uint4(0u, 0u, 0u, 0u);
    if (act) sp = h4[(size_t)node * 16 + ln];  // self term
    float a[8];
    a[0] = bf_lo(sp.x); a[1] = bf_hi(sp.x);
    a[2] = bf_lo(sp.y); a[3] = bf_hi(sp.y);
    a[4] = bf_lo(sp.z); a[5] = bf_hi(sp.z);
    a[6] = bf_lo(sp.w); a[7] = bf_hi(sp.w);
    int s = base_[row];
    int cd = hist[row];
    int end = s + cd;
    for (; s + 8 <= end; s += 8) {
      uint4 u[8];
#pragma unroll
      for (int k = 0; k < 8; ++k) {
        int idx = sorted[s + k];
        u[k] = h4[(size_t)idx * 16 + ln];
      }
#pragma unroll
      for (int k = 0; k < 8; ++k) {
        a[0] += bf_lo(u[k].x); a[1] += bf_hi(u[k].x);
        a[2] += bf_lo(u[k].y); a[3] += bf_hi(u[k].y);
        a[4] += bf_lo(u[k].z); a[5] += bf_hi(u[k].z);
        a[6] += bf_lo(u[k].w); a[7] += bf_hi(u[k].w);
      }
    }
    for (; s + 4 <= end; s += 4) {
      uint4 u[4];
#pragma unroll
      for (int k = 0; k < 4; ++k) {
        int idx = sorted[s + k];
        u[k] = h4[(size_t)idx * 16 + ln];
      }
#pragma unroll
      for (int k = 0; k < 4; ++k) {
        a[0] += bf_lo(u[k].x); a[1] += bf_hi(u[k].x);
        a[2] += bf_lo(u[k].y); a[3] += bf_hi(u[k].y);
        a[4] += bf_lo(u[k].z); a[5] += bf_hi(u[k].z);
        a[6] += bf_lo(u[k].w); a[7] += bf_hi(u[k].w);
      }
    }
    for (; s < end; ++s) {
      int idx = sorted[s];
      uint4 u = h4[(size_t)idx * 16 + ln];
      a[0] += bf_lo(u.x); a[1] += bf_hi(u.x);
      a[2] += bf_lo(u.y); a[3] += bf_hi(u.y);
      a[4] += bf_lo(u.z); a[5] += bf_hi(u.z);
      a[6] += bf_lo(u.w); a[7] += bf_hi(u.w);
    }
    if (act) {
      float di = rsqrtf((float)cd + 1.0f);
      float4 b0 = ((const float4*)bias)[2 * ln];
      float4 b1 = ((const float4*)bias)[2 * ln + 1];
      f32x4 r0, r1;
      r0[0] = fmaf(a[0], di, b0.x); r0[1] = fmaf(a[1], di, b0.y);
      r0[2] = fmaf(a[2], di, b0.z); r0[3] = fmaf(a[3], di, b0.w);
      r1[0] = fmaf(a[4], di, b1.x); r1[1] = fmaf(a[5], di, b1.y);
      r1[2] = fmaf(a[6], di, b1.z); r1[3] = fmaf(a[7], di, b1.w);
      f32x4* op = (f32x4*)(out + (size_t)node * 128 + ln * 8);
      __builtin_nontemporal_store(r0, op);
      __builtin_nontemporal_store(r1, op + 1);
    }
  }
}

// ======================= round-3 CSR fallback =======================

__global__ void k_init(int* __restrict__ cnt, int n) {
  int i = blockIdx.x * blockDim.x + threadIdx.x;
  if (i < n) cnt[i] = 0;
}

__global__ void k_count4(const int* __restrict__ ei, int* __restrict__ cnt, int E) {
  int i = blockIdx.x * blockDim.x + threadIdx.x;
  int e = i * 4;
  if (e + 3 < E) {
    int4 d = *(const int4*)(ei + E + e);
    atomicAdd(&cnt[d.x], 1); atomicAdd(&cnt[d.y], 1);
    atomicAdd(&cnt[d.z], 1); atomicAdd(&cnt[d.w], 1);
  } else {
    for (; e < E; ++e) atomicAdd(&cnt[ei[E + e]], 1);
  }
}

__global__ void k_scan_local(const int* __restrict__ cnt, int* __restrict__ offs,
                             int* __restrict__ bsums, int n) {
  __shared__ int sh[SCAN_T];
  int t = threadIdx.x;
  int base = blockIdx.x * SCAN_E + t * 4;
  int v0 = 0, v1 = 0, v2 = 0, v3 = 0;
  if (base + 0 < n) v0 = cnt[base + 0];
  if (base + 1 < n) v1 = cnt[base + 1];
  if (base + 2 < n) v2 = cnt[base + 2];
  if (base + 3 < n) v3 = cnt[base + 3];
  int sum = v0 + v1 + v2 + v3;
  sh[t] = sum;
  __syncthreads();
  for (int d = 1; d < SCAN_T; d <<= 1) {
    int xv = (t >= d) ? sh[t - d] : 0;
    __syncthreads();
    sh[t] += xv;
    __syncthreads();
  }
  int run = sh[t] - sum;
  if (base + 0 < n) offs[base + 0] = run; run += v0;
  if (base + 1 < n) offs[base + 1] = run; run += v1;
  if (base + 2 < n) offs[base + 2] = run; run += v2;
  if (base + 3 < n) offs[base + 3] = run;
  if (t == SCAN_T - 1) bsums[blockIdx.x] = sh[t];
}

__global__ void k_scan_bsums(int* __restrict__ bsums, int nb) {
  __shared__ int sh[SCAN_T];
  int t = threadIdx.x;
  int v = (t < nb) ? bsums[t] : 0;
  sh[t] = v;
  __syncthreads();
  for (int d = 1; d < SCAN_T; d <<= 1) {
    int xv = (t >= d) ? sh[t - d] : 0;
    __syncthreads();
    sh[t] += xv;
    __syncthreads();
  }
  if (t < nb) bsums[t] = sh[t] - v;
}

__global__ void k_scan_finish(int* __restrict__ offs, const int* __restrict__ bsums,
                              const int* __restrict__ cnt, int* __restrict__ offs2,
                              float* __restrict__ dinv, int n) {
  int i = blockIdx.x * blockDim.x + threadIdx.x;
  if (i < n) {
    int o = offs[i] + bsums[i / SCAN_E];
    offs[i] = o;
    offs2[i] = o;
    dinv[i] = rsqrtf((float)cnt[i] + 1.0f);
  }
}

__global__ void k_fill4(const int* __restrict__ ei, int* __restrict__ offs2,
                        int* __restrict__ csr, int E) {
  int i = blockIdx.x * blockDim.x + threadIdx.x;
  int e = i * 4;
  if (e + 3 < E) {
    int4 s = *(const int4*)(ei + e);
    int4 d = *(const int4*)(ei + E + e);
    csr[atomicAdd(&offs2[d.x], 1)] = s.x;
    csr[atomicAdd(&offs2[d.y], 1)] = s.y;
    csr[atomicAdd(&offs2[d.z], 1)] = s.z;
    csr[atomicAdd(&offs2[d.w], 1)] = s.w;
  } else {
    for (; e < E; ++e) csr[atomicAdd(&offs2[ei[E + e]], 1)] = ei[e];
  }
}

__global__ void __launch_bounds__(256) k_gemm_h(
    const float* __restrict__ x, const float* __restrict__ W,
    const float* __restrict__ dinv, unsigned short* __restrict__ h, int n) {
  __shared__ alignas(16) unsigned short Wt[128][136];
  int t = threadIdx.x;
#pragma unroll
  for (int p = 0; p < 16; ++p) {
    int task = p * 256 + t;
    int kg = task >> 7, nn = task & 127;
    float w0 = W[(kg * 4 + 0) * 128 + nn];
    float w1 = W[(kg * 4 + 1) * 128 + nn];
    float w2 = W[(kg * 4 + 2) * 128 + nn];
    float w3 = W[(kg * 4 + 3) * 128 + nn];
    ushort4 u;
    u.x = f2bf(w0); u.y = f2bf(w1); u.z = f2bf(w2); u.w = f2bf(w3);
    *(ushort4*)&Wt[nn][kg * 4] = u;
  }
  __syncthreads();
  int w = t >> 6, lane = t & 63;
  int q = lane >> 4, m = lane & 15;
  int r0 = blockIdx.x * 64 + w * 16;
  f32x4 acc[8];
#pragma unroll
  for (int nt = 0; nt < 8; ++nt) acc[nt] = (f32x4){0.f, 0.f, 0.f, 0.f};
  float dscale[4];
#pragma unroll
  for (int rg = 0; rg < 4; ++rg) {
    int r = r0 + q * 4 + rg;
    dscale[rg] = dinv[r < n ? r : n - 1];
  }
#pragma unroll
  for (int ks = 0; ks < 4; ++ks) {
    int row = r0 + m;
    row = row < n ? row : n - 1;
    const float* xp = x + (size_t)row * 128 + ks * 32 + q * 8;
    float4 a0 = *(const float4*)xp;
    float4 a1 = *(const float4*)(xp + 4);
    short8 af;
    af[0] = (short)f2bf(a0.x); af[1] = (short)f2bf(a0.y);
    af[2] = (short)f2bf(a0.z); af[3] = (short)f2bf(a0.w);
    af[4] = (short)f2bf(a1.x); af[5] = (short)f2bf(a1.y);
    af[6] = (short)f2bf(a1.z); af[7] = (short)f2bf(a1.w);
#pragma unroll
    for (int nt = 0; nt < 8; ++nt) {
      short8 bf = *(const short8*)&Wt[nt * 16 + m][ks * 32 + q * 8];
      acc[nt] = __builtin_amdgcn_mfma_f32_16x16x32_bf16(af, bf, acc[nt], 0, 0, 0);
    }
  }
#pragma unroll
  for (int nt = 0; nt < 8; ++nt)
#pragma unroll
    for (int rg = 0; rg < 4; ++rg) {
      int r = r0 + q * 4 + rg;
      if (r < n) h[(size_t)r * 128 + nt * 16 + m] = f2bf(acc[nt][rg] * dscale[rg]);
    }
}

__global__ void __launch_bounds__(256) k_agg_bias_csr(
    const unsigned int* __restrict__ h2, const float* __restrict__ dinv,
    const int* __restrict__ offs, const int* __restrict__ cnt,
    const int* __restrict__ csr, const float* __restrict__ bias,
    float* __restrict__ out, int n) {
  int node = blockIdx.x * WPB + (threadIdx.x >> 6);
  int lane = threadIdx.x & 63;
  if (node >= n) return;
  unsigned int sp = h2[(size_t)node * 64 + lane];
  float ax = bf_lo(sp), ay = bf_hi(sp);
  int s = offs[node];
  int end = s + cnt[node];
  for (; s + 8 <= end; s += 8) {
    int i0 = csr[s + 0], i1 = csr[s + 1], i2 = csr[s + 2], i3 = csr[s + 3];
    int i4 = csr[s + 4], i5 = csr[s + 5], i6 = csr[s + 6], i7 = csr[s + 7];
    unsigned int u0 = h2[(size_t)i0 * 64 + lane];
    unsigned int u1 = h2[(size_t)i1 * 64 + lane];
    unsigned int u2 = h2[(size_t)i2 * 64 + lane];
    unsigned int u3 = h2[(size_t)i3 * 64 + lane];
    unsigned int u4 = h2[(size_t)i4 * 64 + lane];
    unsigned int u5 = h2[(size_t)i5 * 64 + lane];
    unsigned int u6 = h2[(size_t)i6 * 64 + lane];
    unsigned int u7 = h2[(size_t)i7 * 64 + lane];
    ax += (bf_lo(u0) + bf_lo(u1)) + (bf_lo(u2) + bf_lo(u3)) +
          (bf_lo(u4) + bf_lo(u5)) + (bf_lo(u6) + bf_lo(u7));
    ay += (bf_hi(u0) + bf_hi(u1)) + (bf_hi(u2) + bf_hi(u3)) +
          (bf_hi(u4) + bf_hi(u5)) + (bf_hi(u6) + bf_hi(u7));
  }
  for (; s < end; ++s) {
    unsigned int u = h2[(size_t)csr[s] * 64 + lane];
    ax += bf_lo(u); ay += bf_hi(u);
  }
  float di = dinv[node];
  float2 bb = ((const float2*)bias)[lane];
  float2 r;
  r.x = fmaf(ax, di, bb.x);
  r.y = fmaf(ay, di, bb.y);
  ((float2*)out)[(size_t)node * 64 + lane] = r;
}

extern "C" void kernel_launch(void* const* d_in, const int* in_sizes, int n_in,
                              void* d_out, int out_size, void* d_ws, size_t ws_size,
                              hipStream_t stream) {
  const float* x = (const float*)d_in[0];
  const int* ei = (const int*)d_in[1];   // harness delivers integers as int32
  const float* Wm = (const float*)d_in[2];
  const float* bias = (const float*)d_in[3];
  float* out = (float*)d_out;

  int N = in_sizes[0] / 128;
  int E = in_sizes[1] / 2;
  int NB = (N + 63) >> 6;

  int nb_n = (N + 255) / 256;
  int nb_e4 = ((E + 3) / 4 + 255) / 256;

  // ---- v11: deg[N] | bcursor[2048] | pairs[NB*CAP] | h[N*128 bf16] ----
  size_t off_bc = ((size_t)N * 4 + 255) & ~(size_t)255;
  size_t off_pairs = off_bc + 8192;
  size_t off_h = (off_pairs + (size_t)NB * CAP * 4 + 255) & ~(size_t)255;
  size_t need11 = off_h + (size_t)N * 256;

  if (ws_size >= need11 && N <= (1 << 17) && NB <= 2048) {
    char* p = (char*)d_ws;
    int* deg = (int*)p;
    int* bcursor = (int*)(p + off_bc);
    int* pairs = (int*)(p + off_pairs);
    unsigned short* h = (unsigned short*)(p + off_h);

    // zero deg + bcursor in one launch (contiguous region)
    int zcnt = (int)(off_pairs / 4);
    k_zero<<<(zcnt + 255) / 256, 256, 0, stream>>>((int*)p, zcnt);
    k_scatter<<<(E + SC_T - 1) / SC_T, 512, 0, stream>>>(ei, deg, bcursor, pairs, E, NB);
    k_gemm_h2<<<NB, 256, 0, stream>>>(x, Wm, deg, h, N);
    k_sort_agg<<<NB, 256, 0, stream>>>(pairs, bcursor, (const uint4*)h, bias, out, N);
    return;
  }

  // ---- round-3 CSR fallback ----
  char* p = (char*)d_ws;
  int* cnt = (int*)p;        p += (size_t)N * 4;
  int* offs = (int*)p;       p += (size_t)N * 4;
  int* offs2 = (int*)p;      p += (size_t)N * 4;
  float* dinv = (float*)p;   p += (size_t)N * 4;
  int* bsums = (int*)p;      p += 1024;
  int* csr = (int*)p;        p += (size_t)E * 4;
  unsigned short* h = (unsigned short*)p;

  int nb_scan = (N + SCAN_E - 1) / SCAN_E;

  k_init<<<nb_n, 256, 0, stream>>>(cnt, N);
  k_count4<<<nb_e4, 256, 0, stream>>>(ei, cnt, E);
  k_scan_local<<<nb_scan, SCAN_T, 0, stream>>>(cnt, offs, bsums, N);
  k_scan_bsums<<<1, SCAN_T, 0, stream>>>(bsums, nb_scan);
  k_scan_finish<<<nb_n, 256, 0, stream>>>(offs, bsums, cnt, offs2, dinv, N);
  k_fill4<<<nb_e4, 256, 0, stream>>>(ei, offs2, csr, E);
  k_gemm_h<<<(N + 63) / 64, 256, 0, stream>>>(x, Wm, dinv, h, N);
  k_agg_bias_csr<<<(N + WPB - 1) / WPB, 256, 0, stream>>>(
      (const unsigned int*)h, dinv, offs, cnt, csr, bias, out, N);
}

// Round 7
// 213.862 us; speedup vs baseline: 6.4386x; 1.2132x over previous
//
#include <hip/hip_runtime.h>

// GCNConv: out = A_hat @ x @ W + b, A_hat = D^-1/2 (A + I) D^-1/2
// v12: k_zero(bcursor) -> k_scatter (v7 form, NO deg atomics — v11's 1.6M
// random global atomics cost ~40us; SC_T 4096 for >1 block/CU) -> k_deg
// (block-per-bucket LDS hist -> dinv, ~5us) -> k_gemm_h (h'=dinv*xW bf16
// MFMA) -> k_sort_agg (LDS counting sort + register-accumulate gather with
// DYNAMIC node claiming to balance Poisson degree tails).

#define SCAN_T 256
#define SCAN_E 1024
#define WPB 4
#define CAP 1536      // bucket capacity (mean 1024, +16 sigma)
#define SC_T 4096     // edges per scatter block -> 391 blocks at E=1.6M

typedef __attribute__((ext_vector_type(8))) short short8;
typedef __attribute__((ext_vector_type(4))) float f32x4;

__device__ __forceinline__ unsigned short f2bf(float f) {
  unsigned int u = __float_as_uint(f);
  u += 0x7FFFu + ((u >> 16) & 1u);   // RNE
  return (unsigned short)(u >> 16);
}
__device__ __forceinline__ float bf_lo(unsigned int u) { return __uint_as_float(u << 16); }
__device__ __forceinline__ float bf_hi(unsigned int u) { return __uint_as_float(u & 0xFFFF0000u); }

// ======================= v12 primary path =======================

__global__ void k_zero(int* __restrict__ p, int m) {
  int i = blockIdx.x * blockDim.x + threadIdx.x;
  if (i < m) p[i] = 0;
}

// Bucket-scatter: pairs[b*CAP + slot] = (dst&63)<<17 | src. (v7 form)
__global__ void __launch_bounds__(512) k_scatter(
    const int* __restrict__ ei, int* __restrict__ bcursor,
    int* __restrict__ pairs, int E, int B) {
  __shared__ int hist[2048];
  int t = threadIdx.x;
  for (int b = t; b < B; b += 512) hist[b] = 0;
  __syncthreads();
  int e0 = blockIdx.x * SC_T;
  int eend = min(e0 + SC_T, E);
  for (int e = e0 + t * 4; e < eend; e += 2048) {
    if (e + 3 < eend) {
      int4 d = *(const int4*)(ei + E + e);
      atomicAdd(&hist[((unsigned)d.x) >> 6], 1);
      atomicAdd(&hist[((unsigned)d.y) >> 6], 1);
      atomicAdd(&hist[((unsigned)d.z) >> 6], 1);
      atomicAdd(&hist[((unsigned)d.w) >> 6], 1);
    } else {
      for (int q = e; q < eend; ++q) atomicAdd(&hist[((unsigned)ei[E + q]) >> 6], 1);
    }
  }
  __syncthreads();
  for (int b = t; b < B; b += 512) {
    int c = hist[b];
    hist[b] = c ? atomicAdd(&bcursor[b], c) : 0;  // base within bucket
  }
  __syncthreads();
  for (int e = e0 + t * 4; e < eend; e += 2048) {
    if (e + 3 < eend) {
      int4 s = *(const int4*)(ei + e);
      int4 d = *(const int4*)(ei + E + e);
      int b0 = ((unsigned)d.x) >> 6; int p0 = atomicAdd(&hist[b0], 1);
      if (p0 < CAP) pairs[(size_t)b0 * CAP + p0] = ((d.x & 63) << 17) | s.x;
      int b1 = ((unsigned)d.y) >> 6; int p1 = atomicAdd(&hist[b1], 1);
      if (p1 < CAP) pairs[(size_t)b1 * CAP + p1] = ((d.y & 63) << 17) | s.y;
      int b2 = ((unsigned)d.z) >> 6; int p2 = atomicAdd(&hist[b2], 1);
      if (p2 < CAP) pairs[(size_t)b2 * CAP + p2] = ((d.z & 63) << 17) | s.z;
      int b3 = ((unsigned)d.w) >> 6; int p3 = atomicAdd(&hist[b3], 1);
      if (p3 < CAP) pairs[(size_t)b3 * CAP + p3] = ((d.w & 63) << 17) | s.w;
    } else {
      for (int q = e; q < eend; ++q) {
        int dst = ei[E + q], src = ei[q];
        int b0 = ((unsigned)dst) >> 6; int p0 = atomicAdd(&hist[b0], 1);
        if (p0 < CAP) pairs[(size_t)b0 * CAP + p0] = ((dst & 63) << 17) | src;
      }
    }
  }
}

// Per-bucket degree count -> dinv. Block b covers nodes b*64..b*64+63.
// Reads pairs (coalesced), LDS hist[64], writes 64 floats. Pure BW, ~5us.
__global__ void __launch_bounds__(256) k_deg(
    const int* __restrict__ pairs, const int* __restrict__ bcursor,
    float* __restrict__ dinv, int n) {
  __shared__ int hist[64];
  int t = threadIdx.x;
  int b = blockIdx.x;
  if (t < 64) hist[t] = 0;
  __syncthreads();
  int cnt = min(bcursor[b], CAP);
  const int* __restrict__ gp = pairs + (size_t)b * CAP;
  for (int i = t; i < cnt; i += 256) atomicAdd(&hist[gp[i] >> 17], 1);
  __syncthreads();
  if (t < 64) {
    int node = b * 64 + t;
    if (node < n) dinv[node] = rsqrtf((float)hist[t] + 1.0f);
  }
}

// bf16 MFMA GEMM: h = dinv * (x @ W).
__global__ void __launch_bounds__(256) k_gemm_h(
    const float* __restrict__ x, const float* __restrict__ W,
    const float* __restrict__ dinv, unsigned short* __restrict__ h, int n) {
  __shared__ alignas(16) unsigned short Wt[128][136];
  int t = threadIdx.x;
#pragma unroll
  for (int p = 0; p < 16; ++p) {
    int task = p * 256 + t;
    int kg = task >> 7, nn = task & 127;
    float w0 = W[(kg * 4 + 0) * 128 + nn];
    float w1 = W[(kg * 4 + 1) * 128 + nn];
    float w2 = W[(kg * 4 + 2) * 128 + nn];
    float w3 = W[(kg * 4 + 3) * 128 + nn];
    ushort4 u;
    u.x = f2bf(w0); u.y = f2bf(w1); u.z = f2bf(w2); u.w = f2bf(w3);
    *(ushort4*)&Wt[nn][kg * 4] = u;
  }
  __syncthreads();
  int w = t >> 6, lane = t & 63;
  int q = lane >> 4, m = lane & 15;
  int r0 = blockIdx.x * 64 + w * 16;
  f32x4 acc[8];
#pragma unroll
  for (int nt = 0; nt < 8; ++nt) acc[nt] = (f32x4){0.f, 0.f, 0.f, 0.f};
  float dscale[4];
#pragma unroll
  for (int rg = 0; rg < 4; ++rg) {
    int r = r0 + q * 4 + rg;
    dscale[rg] = dinv[r < n ? r : n - 1];
  }
#pragma unroll
  for (int ks = 0; ks < 4; ++ks) {
    int row = r0 + m;
    row = row < n ? row : n - 1;
    const float* xp = x + (size_t)row * 128 + ks * 32 + q * 8;
    float4 a0 = *(const float4*)xp;
    float4 a1 = *(const float4*)(xp + 4);
    short8 af;
    af[0] = (short)f2bf(a0.x); af[1] = (short)f2bf(a0.y);
    af[2] = (short)f2bf(a0.z); af[3] = (short)f2bf(a0.w);
    af[4] = (short)f2bf(a1.x); af[5] = (short)f2bf(a1.y);
    af[6] = (short)f2bf(a1.z); af[7] = (short)f2bf(a1.w);
#pragma unroll
    for (int nt = 0; nt < 8; ++nt) {
      short8 bf = *(const short8*)&Wt[nt * 16 + m][ks * 32 + q * 8];
      acc[nt] = __builtin_amdgcn_mfma_f32_16x16x32_bf16(af, bf, acc[nt], 0, 0, 0);
    }
  }
#pragma unroll
  for (int nt = 0; nt < 8; ++nt)
#pragma unroll
    for (int rg = 0; rg < 4; ++rg) {
      int r = r0 + q * 4 + rg;
      if (r < n) h[(size_t)r * 128 + nt * 16 + m] = f2bf(acc[nt][rg] * dscale[rg]);
    }
}

// Fused sort + aggregate. Block b == bucket b == nodes b*64..b*64+63.
// Phase 1: LDS counting sort -> sorted[] src lists grouped by dl.
// Phase 2: 16-lane groups DYNAMICALLY claim nodes from an LDS counter
// (balances Poisson degree tails), gather h[src] rows (uint4, 8-deep
// unroll, register accumulate), out = dinv*a + bias, nt stores.
__global__ void __launch_bounds__(256) k_sort_agg(
    const int* __restrict__ pairs, const int* __restrict__ bcursor,
    const uint4* __restrict__ h4, const float* __restrict__ bias,
    float* __restrict__ out, int n) {
  __shared__ int pb[CAP];
  __shared__ int sorted[CAP];
  __shared__ int hist[64], base_[64], cur[64];
  __shared__ int nextn;
  int t = threadIdx.x;
  int b = blockIdx.x;
  if (t < 64) { hist[t] = 0; cur[t] = 0; }
  if (t == 0) nextn = 0;
  __syncthreads();
  int cnt = min(bcursor[b], CAP);
  const int* __restrict__ gp = pairs + (size_t)b * CAP;
  for (int i = t; i < cnt; i += 256) {
    int p = gp[i];
    pb[i] = p;
    atomicAdd(&hist[p >> 17], 1);
  }
  __syncthreads();
  if (t < 64) {  // wave 0: inclusive scan via shuffles
    int v = hist[t];
    int incl = v;
#pragma unroll
    for (int d = 1; d < 64; d <<= 1) {
      int u = __shfl_up(incl, d, 64);
      if (t >= d) incl += u;
    }
    base_[t] = incl - v;
  }
  __syncthreads();
  for (int i = t; i < cnt; i += 256) {
    int p = pb[i];
    int d = p >> 17;
    int pos = base_[d] + atomicAdd(&cur[d], 1);
    sorted[pos] = p & 0x1FFFF;
  }
  __syncthreads();

  // ---- phase 2: gather-aggregate with dynamic node claiming ----
  int lane = t & 63;
  int ln = lane & 15;
  int nbase = b << 6;
  for (;;) {
    int row = 0;
    if (ln == 0) row = atomicAdd(&nextn, 1);
    row = __shfl(row, lane & 48, 64);   // broadcast to the 16-lane group
    if (row >= 64) break;
    int node = nbase + row;
    bool act = node < n;
    uint4 sp = make_uint4(0u, 0u, 0u, 0u);
    if (act) sp = h4[(size_t)node * 16 + ln];  // self term
    float a[8];
    a[0] = bf_lo(sp.x); a[1] = bf_hi(sp.x);
    a[2] = bf_lo(sp.y); a[3] = bf_hi(sp.y);
    a[4] = bf_lo(sp.z); a[5] = bf_hi(sp.z);
    a[6] = bf_lo(sp.w); a[7] = bf_hi(sp.w);
    int s = base_[row];
    int cd = hist[row];
    int end = s + cd;
    for (; s + 8 <= end; s += 8) {
      uint4 u[8];
#pragma unroll
      for (int k = 0; k < 8; ++k) {
        int idx = sorted[s + k];
        u[k] = h4[(size_t)idx * 16 + ln];
      }
#pragma unroll
      for (int k = 0; k < 8; ++k) {
        a[0] += bf_lo(u[k].x); a[1] += bf_hi(u[k].x);
        a[2] += bf_lo(u[k].y); a[3] += bf_hi(u[k].y);
        a[4] += bf_lo(u[k].z); a[5] += bf_hi(u[k].z);
        a[6] += bf_lo(u[k].w); a[7] += bf_hi(u[k].w);
      }
    }
    for (; s + 4 <= end; s += 4) {
      uint4 u[4];
#pragma unroll
      for (int k = 0; k < 4; ++k) {
        int idx = sorted[s + k];
        u[k] = h4[(size_t)idx * 16 + ln];
      }
#pragma unroll
      for (int k = 0; k < 4; ++k) {
        a[0] += bf_lo(u[k].x); a[1] += bf_hi(u[k].x);
        a[2] += bf_lo(u[k].y); a[3] += bf_hi(u[k].y);
        a[4] += bf_lo(u[k].z); a[5] += bf_hi(u[k].z);
        a[6] += bf_lo(u[k].w); a[7] += bf_hi(u[k].w);
      }
    }
    for (; s < end; ++s) {
      int idx = sorted[s];
      uint4 u = h4[(size_t)idx * 16 + ln];
      a[0] += bf_lo(u.x); a[1] += bf_hi(u.x);
      a[2] += bf_lo(u.y); a[3] += bf_hi(u.y);
      a[4] += bf_lo(u.z); a[5] += bf_hi(u.z);
      a[6] += bf_lo(u.w); a[7] += bf_hi(u.w);
    }
    if (act) {
      float di = rsqrtf((float)cd + 1.0f);
      float4 b0 = ((const float4*)bias)[2 * ln];
      float4 b1 = ((const float4*)bias)[2 * ln + 1];
      f32x4 r0, r1;
      r0[0] = fmaf(a[0], di, b0.x); r0[1] = fmaf(a[1], di, b0.y);
      r0[2] = fmaf(a[2], di, b0.z); r0[3] = fmaf(a[3], di, b0.w);
      r1[0] = fmaf(a[4], di, b1.x); r1[1] = fmaf(a[5], di, b1.y);
      r1[2] = fmaf(a[6], di, b1.z); r1[3] = fmaf(a[7], di, b1.w);
      f32x4* op = (f32x4*)(out + (size_t)node * 128 + ln * 8);
      __builtin_nontemporal_store(r0, op);
      __builtin_nontemporal_store(r1, op + 1);
    }
  }
}

// ======================= round-3 CSR fallback =======================

__global__ void k_init(int* __restrict__ cnt, int n) {
  int i = blockIdx.x * blockDim.x + threadIdx.x;
  if (i < n) cnt[i] = 0;
}

__global__ void k_count4(const int* __restrict__ ei, int* __restrict__ cnt, int E) {
  int i = blockIdx.x * blockDim.x + threadIdx.x;
  int e = i * 4;
  if (e + 3 < E) {
    int4 d = *(const int4*)(ei + E + e);
    atomicAdd(&cnt[d.x], 1); atomicAdd(&cnt[d.y], 1);
    atomicAdd(&cnt[d.z], 1); atomicAdd(&cnt[d.w], 1);
  } else {
    for (; e < E; ++e) atomicAdd(&cnt[ei[E + e]], 1);
  }
}

__global__ void k_scan_local(const int* __restrict__ cnt, int* __restrict__ offs,
                             int* __restrict__ bsums, int n) {
  __shared__ int sh[SCAN_T];
  int t = threadIdx.x;
  int base = blockIdx.x * SCAN_E + t * 4;
  int v0 = 0, v1 = 0, v2 = 0, v3 = 0;
  if (base + 0 < n) v0 = cnt[base + 0];
  if (base + 1 < n) v1 = cnt[base + 1];
  if (base + 2 < n) v2 = cnt[base + 2];
  if (base + 3 < n) v3 = cnt[base + 3];
  int sum = v0 + v1 + v2 + v3;
  sh[t] = sum;
  __syncthreads();
  for (int d = 1; d < SCAN_T; d <<= 1) {
    int xv = (t >= d) ? sh[t - d] : 0;
    __syncthreads();
    sh[t] += xv;
    __syncthreads();
  }
  int run = sh[t] - sum;
  if (base + 0 < n) offs[base + 0] = run; run += v0;
  if (base + 1 < n) offs[base + 1] = run; run += v1;
  if (base + 2 < n) offs[base + 2] = run; run += v2;
  if (base + 3 < n) offs[base + 3] = run;
  if (t == SCAN_T - 1) bsums[blockIdx.x] = sh[t];
}

__global__ void k_scan_bsums(int* __restrict__ bsums, int nb) {
  __shared__ int sh[SCAN_T];
  int t = threadIdx.x;
  int v = (t < nb) ? bsums[t] : 0;
  sh[t] = v;
  __syncthreads();
  for (int d = 1; d < SCAN_T; d <<= 1) {
    int xv = (t >= d) ? sh[t - d] : 0;
    __syncthreads();
    sh[t] += xv;
    __syncthreads();
  }
  if (t < nb) bsums[t] = sh[t] - v;
}

__global__ void k_scan_finish(int* __restrict__ offs, const int* __restrict__ bsums,
                              const int* __restrict__ cnt, int* __restrict__ offs2,
                              float* __restrict__ dinv, int n) {
  int i = blockIdx.x * blockDim.x + threadIdx.x;
  if (i < n) {
    int o = offs[i] + bsums[i / SCAN_E];
    offs[i] = o;
    offs2[i] = o;
    dinv[i] = rsqrtf((float)cnt[i] + 1.0f);
  }
}

__global__ void k_fill4(const int* __restrict__ ei, int* __restrict__ offs2,
                        int* __restrict__ csr, int E) {
  int i = blockIdx.x * blockDim.x + threadIdx.x;
  int e = i * 4;
  if (e + 3 < E) {
    int4 s = *(const int4*)(ei + e);
    int4 d = *(const int4*)(ei + E + e);
    csr[atomicAdd(&offs2[d.x], 1)] = s.x;
    csr[atomicAdd(&offs2[d.y], 1)] = s.y;
    csr[atomicAdd(&offs2[d.z], 1)] = s.z;
    csr[atomicAdd(&offs2[d.w], 1)] = s.w;
  } else {
    for (; e < E; ++e) csr[atomicAdd(&offs2[ei[E + e]], 1)] = ei[e];
  }
}

__global__ void __launch_bounds__(256) k_agg_bias_csr(
    const unsigned int* __restrict__ h2, const float* __restrict__ dinv,
    const int* __restrict__ offs, const int* __restrict__ cnt,
    const int* __restrict__ csr, const float* __restrict__ bias,
    float* __restrict__ out, int n) {
  int node = blockIdx.x * WPB + (threadIdx.x >> 6);
  int lane = threadIdx.x & 63;
  if (node >= n) return;
  unsigned int sp = h2[(size_t)node * 64 + lane];
  float ax = bf_lo(sp), ay = bf_hi(sp);
  int s = offs[node];
  int end = s + cnt[node];
  for (; s + 8 <= end; s += 8) {
    int i0 = csr[s + 0], i1 = csr[s + 1], i2 = csr[s + 2], i3 = csr[s + 3];
    int i4 = csr[s + 4], i5 = csr[s + 5], i6 = csr[s + 6], i7 = csr[s + 7];
    unsigned int u0 = h2[(size_t)i0 * 64 + lane];
    unsigned int u1 = h2[(size_t)i1 * 64 + lane];
    unsigned int u2 = h2[(size_t)i2 * 64 + lane];
    unsigned int u3 = h2[(size_t)i3 * 64 + lane];
    unsigned int u4 = h2[(size_t)i4 * 64 + lane];
    unsigned int u5 = h2[(size_t)i5 * 64 + lane];
    unsigned int u6 = h2[(size_t)i6 * 64 + lane];
    unsigned int u7 = h2[(size_t)i7 * 64 + lane];
    ax += (bf_lo(u0) + bf_lo(u1)) + (bf_lo(u2) + bf_lo(u3)) +
          (bf_lo(u4) + bf_lo(u5)) + (bf_lo(u6) + bf_lo(u7));
    ay += (bf_hi(u0) + bf_hi(u1)) + (bf_hi(u2) + bf_hi(u3)) +
          (bf_hi(u4) + bf_hi(u5)) + (bf_hi(u6) + bf_hi(u7));
  }
  for (; s < end; ++s) {
    unsigned int u = h2[(size_t)csr[s] * 64 + lane];
    ax += bf_lo(u); ay += bf_hi(u);
  }
  float di = dinv[node];
  float2 bb = ((const float2*)bias)[lane];
  float2 r;
  r.x = fmaf(ax, di, bb.x);
  r.y = fmaf(ay, di, bb.y);
  ((float2*)out)[(size_t)node * 64 + lane] = r;
}

extern "C" void kernel_launch(void* const* d_in, const int* in_sizes, int n_in,
                              void* d_out, int out_size, void* d_ws, size_t ws_size,
                              hipStream_t stream) {
  const float* x = (const float*)d_in[0];
  const int* ei = (const int*)d_in[1];   // harness delivers integers as int32
  const float* Wm = (const float*)d_in[2];
  const float* bias = (const float*)d_in[3];
  float* out = (float*)d_out;

  int N = in_sizes[0] / 128;
  int E = in_sizes[1] / 2;
  int NB = (N + 63) >> 6;

  int nb_n = (N + 255) / 256;
  int nb_e4 = ((E + 3) / 4 + 255) / 256;

  // ---- v12: dinv[N floats] | bcursor[2048] | pairs[NB*CAP] | h[N*128 bf16] ----
  size_t off_bc = ((size_t)N * 4 + 255) & ~(size_t)255;
  size_t off_pairs = off_bc + 8192;
  size_t off_h = (off_pairs + (size_t)NB * CAP * 4 + 255) & ~(size_t)255;
  size_t need12 = off_h + (size_t)N * 256;

  if (ws_size >= need12 && N <= (1 << 17) && NB <= 2048) {
    char* p = (char*)d_ws;
    float* dinv = (float*)p;
    int* bcursor = (int*)(p + off_bc);
    int* pairs = (int*)(p + off_pairs);
    unsigned short* h = (unsigned short*)(p + off_h);

    k_zero<<<8, 256, 0, stream>>>(bcursor, 2048);
    k_scatter<<<(E + SC_T - 1) / SC_T, 512, 0, stream>>>(ei, bcursor, pairs, E, NB);
    k_deg<<<NB, 256, 0, stream>>>(pairs, bcursor, dinv, N);
    k_gemm_h<<<NB, 256, 0, stream>>>(x, Wm, dinv, h, N);
    k_sort_agg<<<NB, 256, 0, stream>>>(pairs, bcursor, (const uint4*)h, bias, out, N);
    return;
  }

  // ---- round-3 CSR fallback ----
  char* p = (char*)d_ws;
  int* cnt = (int*)p;        p += (size_t)N * 4;
  int* offs = (int*)p;       p += (size_t)N * 4;
  int* offs2 = (int*)p;      p += (size_t)N * 4;
  float* dinv = (float*)p;   p += (size_t)N * 4;
  int* bsums = (int*)p;      p += 1024;
  int* csr = (int*)p;        p += (size_t)E * 4;
  unsigned short* h = (unsigned short*)p;

  int nb_scan = (N + SCAN_E - 1) / SCAN_E;

  k_init<<<nb_n, 256, 0, stream>>>(cnt, N);
  k_count4<<<nb_e4, 256, 0, stream>>>(ei, cnt, E);
  k_scan_local<<<nb_scan, SCAN_T, 0, stream>>>(cnt, offs, bsums, N);
  k_scan_bsums<<<1, SCAN_T, 0, stream>>>(bsums, nb_scan);
  k_scan_finish<<<nb_n, 256, 0, stream>>>(offs, bsums, cnt, offs2, dinv, N);
  k_fill4<<<nb_e4, 256, 0, stream>>>(ei, offs2, csr, E);
  k_gemm_h<<<(N + 63) / 64, 256, 0, stream>>>(x, Wm, dinv, h, N);
  k_agg_bias_csr<<<(N + WPB - 1) / WPB, 256, 0, stream>>>(
      (const unsigned int*)h, dinv, offs, cnt, csr, bias, out, N);
}

// Round 8
// 205.373 us; speedup vs baseline: 6.7047x; 1.0413x over previous
//
#include <hip/hip_runtime.h>

// GCNConv: out = A_hat @ x @ W + b, A_hat = D^-1/2 (A + I) D^-1/2
// v13: 128-node buckets (B=782). k_zero -> k_scatter (2-pass LDS histogram;
// ~10.5 consecutive slots/bucket/block at SC_T=8192 cuts 4B-store write
// amplification ~3x vs 64-node buckets) -> k_deg (bucket hist -> dinv) ->
// k_gemm_h (bf16 MFMA, h' = dinv*xW) -> k_sort_agg (512 thr: LDS counting
// sort of 2048-pair bucket + 32 dynamic-claiming 16-lane groups gathering
// h[src] rows uint4 8-deep, register accumulate, nt out stores).

#define SCAN_T 256
#define SCAN_E 1024
#define WPB 4
#define CAP 2560      // pairs per 128-node bucket (mean 2048, +11 sigma)
#define SC_T 8192     // edges per scatter block -> 196 blocks at E=1.6M

typedef __attribute__((ext_vector_type(8))) short short8;
typedef __attribute__((ext_vector_type(4))) float f32x4;

__device__ __forceinline__ unsigned short f2bf(float f) {
  unsigned int u = __float_as_uint(f);
  u += 0x7FFFu + ((u >> 16) & 1u);   // RNE
  return (unsigned short)(u >> 16);
}
__device__ __forceinline__ float bf_lo(unsigned int u) { return __uint_as_float(u << 16); }
__device__ __forceinline__ float bf_hi(unsigned int u) { return __uint_as_float(u & 0xFFFF0000u); }

// ======================= v13 primary path =======================

__global__ void k_zero(int* __restrict__ p, int m) {
  int i = blockIdx.x * blockDim.x + threadIdx.x;
  if (i < m) p[i] = 0;
}

// Bucket-scatter: pairs[b*CAP + slot] = (dst&127)<<17 | src. bucket = dst>>7.
__global__ void __launch_bounds__(512) k_scatter(
    const int* __restrict__ ei, int* __restrict__ bcursor,
    int* __restrict__ pairs, int E, int B) {
  __shared__ int hist[1024];
  int t = threadIdx.x;
  for (int b = t; b < B; b += 512) hist[b] = 0;
  __syncthreads();
  int e0 = blockIdx.x * SC_T;
  int eend = min(e0 + SC_T, E);
  for (int e = e0 + t * 4; e < eend; e += 2048) {
    if (e + 3 < eend) {
      int4 d = *(const int4*)(ei + E + e);
      atomicAdd(&hist[((unsigned)d.x) >> 7], 1);
      atomicAdd(&hist[((unsigned)d.y) >> 7], 1);
      atomicAdd(&hist[((unsigned)d.z) >> 7], 1);
      atomicAdd(&hist[((unsigned)d.w) >> 7], 1);
    } else {
      for (int q = e; q < eend; ++q) atomicAdd(&hist[((unsigned)ei[E + q]) >> 7], 1);
    }
  }
  __syncthreads();
  for (int b = t; b < B; b += 512) {
    int c = hist[b];
    hist[b] = c ? atomicAdd(&bcursor[b], c) : 0;  // base within bucket
  }
  __syncthreads();
  for (int e = e0 + t * 4; e < eend; e += 2048) {
    if (e + 3 < eend) {
      int4 s = *(const int4*)(ei + e);
      int4 d = *(const int4*)(ei + E + e);
      int b0 = ((unsigned)d.x) >> 7; int p0 = atomicAdd(&hist[b0], 1);
      if (p0 < CAP) pairs[(size_t)b0 * CAP + p0] = ((d.x & 127) << 17) | s.x;
      int b1 = ((unsigned)d.y) >> 7; int p1 = atomicAdd(&hist[b1], 1);
      if (p1 < CAP) pairs[(size_t)b1 * CAP + p1] = ((d.y & 127) << 17) | s.y;
      int b2 = ((unsigned)d.z) >> 7; int p2 = atomicAdd(&hist[b2], 1);
      if (p2 < CAP) pairs[(size_t)b2 * CAP + p2] = ((d.z & 127) << 17) | s.z;
      int b3 = ((unsigned)d.w) >> 7; int p3 = atomicAdd(&hist[b3], 1);
      if (p3 < CAP) pairs[(size_t)b3 * CAP + p3] = ((d.w & 127) << 17) | s.w;
    } else {
      for (int q = e; q < eend; ++q) {
        int dst = ei[E + q], src = ei[q];
        int b0 = ((unsigned)dst) >> 7; int p0 = atomicAdd(&hist[b0], 1);
        if (p0 < CAP) pairs[(size_t)b0 * CAP + p0] = ((dst & 127) << 17) | src;
      }
    }
  }
}

// Per-bucket degree count -> dinv. Block b covers nodes b*128..b*128+127.
__global__ void __launch_bounds__(256) k_deg(
    const int* __restrict__ pairs, const int* __restrict__ bcursor,
    float* __restrict__ dinv, int n) {
  __shared__ int hist[128];
  int t = threadIdx.x;
  int b = blockIdx.x;
  if (t < 128) hist[t] = 0;
  __syncthreads();
  int cnt = min(bcursor[b], CAP);
  const int* __restrict__ gp = pairs + (size_t)b * CAP;
  for (int i = t; i < cnt; i += 256) atomicAdd(&hist[gp[i] >> 17], 1);
  __syncthreads();
  if (t < 128) {
    int node = b * 128 + t;
    if (node < n) dinv[node] = rsqrtf((float)hist[t] + 1.0f);
  }
}

// bf16 MFMA GEMM: h = dinv * (x @ W).
__global__ void __launch_bounds__(256) k_gemm_h(
    const float* __restrict__ x, const float* __restrict__ W,
    const float* __restrict__ dinv, unsigned short* __restrict__ h, int n) {
  __shared__ alignas(16) unsigned short Wt[128][136];
  int t = threadIdx.x;
#pragma unroll
  for (int p = 0; p < 16; ++p) {
    int task = p * 256 + t;
    int kg = task >> 7, nn = task & 127;
    float w0 = W[(kg * 4 + 0) * 128 + nn];
    float w1 = W[(kg * 4 + 1) * 128 + nn];
    float w2 = W[(kg * 4 + 2) * 128 + nn];
    float w3 = W[(kg * 4 + 3) * 128 + nn];
    ushort4 u;
    u.x = f2bf(w0); u.y = f2bf(w1); u.z = f2bf(w2); u.w = f2bf(w3);
    *(ushort4*)&Wt[nn][kg * 4] = u;
  }
  __syncthreads();
  int w = t >> 6, lane = t & 63;
  int q = lane >> 4, m = lane & 15;
  int r0 = blockIdx.x * 64 + w * 16;
  f32x4 acc[8];
#pragma unroll
  for (int nt = 0; nt < 8; ++nt) acc[nt] = (f32x4){0.f, 0.f, 0.f, 0.f};
  float dscale[4];
#pragma unroll
  for (int rg = 0; rg < 4; ++rg) {
    int r = r0 + q * 4 + rg;
    dscale[rg] = dinv[r < n ? r : n - 1];
  }
#pragma unroll
  for (int ks = 0; ks < 4; ++ks) {
    int row = r0 + m;
    row = row < n ? row : n - 1;
    const float* xp = x + (size_t)row * 128 + ks * 32 + q * 8;
    float4 a0 = *(const float4*)xp;
    float4 a1 = *(const float4*)(xp + 4);
    short8 af;
    af[0] = (short)f2bf(a0.x); af[1] = (short)f2bf(a0.y);
    af[2] = (short)f2bf(a0.z); af[3] = (short)f2bf(a0.w);
    af[4] = (short)f2bf(a1.x); af[5] = (short)f2bf(a1.y);
    af[6] = (short)f2bf(a1.z); af[7] = (short)f2bf(a1.w);
#pragma unroll
    for (int nt = 0; nt < 8; ++nt) {
      short8 bf = *(const short8*)&Wt[nt * 16 + m][ks * 32 + q * 8];
      acc[nt] = __builtin_amdgcn_mfma_f32_16x16x32_bf16(af, bf, acc[nt], 0, 0, 0);
    }
  }
#pragma unroll
  for (int nt = 0; nt < 8; ++nt)
#pragma unroll
    for (int rg = 0; rg < 4; ++rg) {
      int r = r0 + q * 4 + rg;
      if (r < n) h[(size_t)r * 128 + nt * 16 + m] = f2bf(acc[nt][rg] * dscale[rg]);
    }
}

// Fused sort + aggregate for a 128-node bucket, 512 threads.
// Phase 1: LDS counting sort -> sorted[] src lists grouped by dl (0..127).
// Phase 2: 32 16-lane groups dynamically claim nodes; gather h[src] rows
// (uint4, 8-deep unroll, register accumulate); out = dinv*a + bias, nt store.
__global__ void __launch_bounds__(512) k_sort_agg(
    const int* __restrict__ pairs, const int* __restrict__ bcursor,
    const uint4* __restrict__ h4, const float* __restrict__ bias,
    float* __restrict__ out, int n) {
  __shared__ int pb[CAP];
  __shared__ int sorted[CAP];
  __shared__ int hist[128], base_[128], cur[128];
  __shared__ int nextn;
  int t = threadIdx.x;
  int b = blockIdx.x;
  if (t < 128) { hist[t] = 0; cur[t] = 0; }
  if (t == 0) nextn = 0;
  __syncthreads();
  int cnt = min(bcursor[b], CAP);
  const int* __restrict__ gp = pairs + (size_t)b * CAP;
  for (int i = t; i < cnt; i += 512) {
    int p = gp[i];
    pb[i] = p;
    atomicAdd(&hist[p >> 17], 1);
  }
  __syncthreads();
  // inclusive scan of hist[128] via LDS Hillis-Steele into base_ (exclusive)
  if (t < 128) base_[t] = hist[t];
  __syncthreads();
#pragma unroll
  for (int d = 1; d < 128; d <<= 1) {
    int v = (t < 128 && t >= d) ? base_[t - d] : 0;
    __syncthreads();
    if (t < 128) base_[t] += v;
    __syncthreads();
  }
  if (t < 128) base_[t] -= hist[t];
  __syncthreads();
  for (int i = t; i < cnt; i += 512) {
    int p = pb[i];
    int d = p >> 17;
    int pos = base_[d] + atomicAdd(&cur[d], 1);
    sorted[pos] = p & 0x1FFFF;
  }
  __syncthreads();

  // ---- phase 2: gather-aggregate with dynamic node claiming ----
  int lane = t & 63;
  int ln = lane & 15;
  int nbase = b << 7;
  for (;;) {
    int row = 0;
    if (ln == 0) row = atomicAdd(&nextn, 1);
    row = __shfl(row, lane & 48, 64);   // broadcast to the 16-lane group
    if (row >= 128) break;
    int node = nbase + row;
    bool act = node < n;
    uint4 sp = make_uint4(0u, 0u, 0u, 0u);
    if (act) sp = h4[(size_t)node * 16 + ln];  // self term
    float a[8];
    a[0] = bf_lo(sp.x); a[1] = bf_hi(sp.x);
    a[2] = bf_lo(sp.y); a[3] = bf_hi(sp.y);
    a[4] = bf_lo(sp.z); a[5] = bf_hi(sp.z);
    a[6] = bf_lo(sp.w); a[7] = bf_hi(sp.w);
    int s = base_[row];
    int cd = hist[row];
    int end = s + cd;
    for (; s + 8 <= end; s += 8) {
      uint4 u[8];
#pragma unroll
      for (int k = 0; k < 8; ++k) {
        int idx = sorted[s + k];
        u[k] = h4[(size_t)idx * 16 + ln];
      }
#pragma unroll
      for (int k = 0; k < 8; ++k) {
        a[0] += bf_lo(u[k].x); a[1] += bf_hi(u[k].x);
        a[2] += bf_lo(u[k].y); a[3] += bf_hi(u[k].y);
        a[4] += bf_lo(u[k].z); a[5] += bf_hi(u[k].z);
        a[6] += bf_lo(u[k].w); a[7] += bf_hi(u[k].w);
      }
    }
    for (; s + 4 <= end; s += 4) {
      uint4 u[4];
#pragma unroll
      for (int k = 0; k < 4; ++k) {
        int idx = sorted[s + k];
        u[k] = h4[(size_t)idx * 16 + ln];
      }
#pragma unroll
      for (int k = 0; k < 4; ++k) {
        a[0] += bf_lo(u[k].x); a[1] += bf_hi(u[k].x);
        a[2] += bf_lo(u[k].y); a[3] += bf_hi(u[k].y);
        a[4] += bf_lo(u[k].z); a[5] += bf_hi(u[k].z);
        a[6] += bf_lo(u[k].w); a[7] += bf_hi(u[k].w);
      }
    }
    for (; s < end; ++s) {
      int idx = sorted[s];
      uint4 u = h4[(size_t)idx * 16 + ln];
      a[0] += bf_lo(u.x); a[1] += bf_hi(u.x);
      a[2] += bf_lo(u.y); a[3] += bf_hi(u.y);
      a[4] += bf_lo(u.z); a[5] += bf_hi(u.z);
      a[6] += bf_lo(u.w); a[7] += bf_hi(u.w);
    }
    if (act) {
      float di = rsqrtf((float)cd + 1.0f);
      float4 b0 = ((const float4*)bias)[2 * ln];
      float4 b1 = ((const float4*)bias)[2 * ln + 1];
      f32x4 r0, r1;
      r0[0] = fmaf(a[0], di, b0.x); r0[1] = fmaf(a[1], di, b0.y);
      r0[2] = fmaf(a[2], di, b0.z); r0[3] = fmaf(a[3], di, b0.w);
      r1[0] = fmaf(a[4], di, b1.x); r1[1] = fmaf(a[5], di, b1.y);
      r1[2] = fmaf(a[6], di, b1.z); r1[3] = fmaf(a[7], di, b1.w);
      f32x4* op = (f32x4*)(out + (size_t)node * 128 + ln * 8);
      __builtin_nontemporal_store(r0, op);
      __builtin_nontemporal_store(r1, op + 1);
    }
  }
}

// ======================= round-3 CSR fallback =======================

__global__ void k_init(int* __restrict__ cnt, int n) {
  int i = blockIdx.x * blockDim.x + threadIdx.x;
  if (i < n) cnt[i] = 0;
}

__global__ void k_count4(const int* __restrict__ ei, int* __restrict__ cnt, int E) {
  int i = blockIdx.x * blockDim.x + threadIdx.x;
  int e = i * 4;
  if (e + 3 < E) {
    int4 d = *(const int4*)(ei + E + e);
    atomicAdd(&cnt[d.x], 1); atomicAdd(&cnt[d.y], 1);
    atomicAdd(&cnt[d.z], 1); atomicAdd(&cnt[d.w], 1);
  } else {
    for (; e < E; ++e) atomicAdd(&cnt[ei[E + e]], 1);
  }
}

__global__ void k_scan_local(const int* __restrict__ cnt, int* __restrict__ offs,
                             int* __restrict__ bsums, int n) {
  __shared__ int sh[SCAN_T];
  int t = threadIdx.x;
  int base = blockIdx.x * SCAN_E + t * 4;
  int v0 = 0, v1 = 0, v2 = 0, v3 = 0;
  if (base + 0 < n) v0 = cnt[base + 0];
  if (base + 1 < n) v1 = cnt[base + 1];
  if (base + 2 < n) v2 = cnt[base + 2];
  if (base + 3 < n) v3 = cnt[base + 3];
  int sum = v0 + v1 + v2 + v3;
  sh[t] = sum;
  __syncthreads();
  for (int d = 1; d < SCAN_T; d <<= 1) {
    int xv = (t >= d) ? sh[t - d] : 0;
    __syncthreads();
    sh[t] += xv;
    __syncthreads();
  }
  int run = sh[t] - sum;
  if (base + 0 < n) offs[base + 0] = run; run += v0;
  if (base + 1 < n) offs[base + 1] = run; run += v1;
  if (base + 2 < n) offs[base + 2] = run; run += v2;
  if (base + 3 < n) offs[base + 3] = run;
  if (t == SCAN_T - 1) bsums[blockIdx.x] = sh[t];
}

__global__ void k_scan_bsums(int* __restrict__ bsums, int nb) {
  __shared__ int sh[SCAN_T];
  int t = threadIdx.x;
  int v = (t < nb) ? bsums[t] : 0;
  sh[t] = v;
  __syncthreads();
  for (int d = 1; d < SCAN_T; d <<= 1) {
    int xv = (t >= d) ? sh[t - d] : 0;
    __syncthreads();
    sh[t] += xv;
    __syncthreads();
  }
  if (t < nb) bsums[t] = sh[t] - v;
}

__global__ void k_scan_finish(int* __restrict__ offs, const int* __restrict__ bsums,
                              const int* __restrict__ cnt, int* __restrict__ offs2,
                              float* __restrict__ dinv, int n) {
  int i = blockIdx.x * blockDim.x + threadIdx.x;
  if (i < n) {
    int o = offs[i] + bsums[i / SCAN_E];
    offs[i] = o;
    offs2[i] = o;
    dinv[i] = rsqrtf((float)cnt[i] + 1.0f);
  }
}

__global__ void k_fill4(const int* __restrict__ ei, int* __restrict__ offs2,
                        int* __restrict__ csr, int E) {
  int i = blockIdx.x * blockDim.x + threadIdx.x;
  int e = i * 4;
  if (e + 3 < E) {
    int4 s = *(const int4*)(ei + e);
    int4 d = *(const int4*)(ei + E + e);
    csr[atomicAdd(&offs2[d.x], 1)] = s.x;
    csr[atomicAdd(&offs2[d.y], 1)] = s.y;
    csr[atomicAdd(&offs2[d.z], 1)] = s.z;
    csr[atomicAdd(&offs2[d.w], 1)] = s.w;
  } else {
    for (; e < E; ++e) csr[atomicAdd(&offs2[ei[E + e]], 1)] = ei[e];
  }
}

__global__ void __launch_bounds__(256) k_agg_bias_csr(
    const unsigned int* __restrict__ h2, const float* __restrict__ dinv,
    const int* __restrict__ offs, const int* __restrict__ cnt,
    const int* __restrict__ csr, const float* __restrict__ bias,
    float* __restrict__ out, int n) {
  int node = blockIdx.x * WPB + (threadIdx.x >> 6);
  int lane = threadIdx.x & 63;
  if (node >= n) return;
  unsigned int sp = h2[(size_t)node * 64 + lane];
  float ax = bf_lo(sp), ay = bf_hi(sp);
  int s = offs[node];
  int end = s + cnt[node];
  for (; s + 8 <= end; s += 8) {
    int i0 = csr[s + 0], i1 = csr[s + 1], i2 = csr[s + 2], i3 = csr[s + 3];
    int i4 = csr[s + 4], i5 = csr[s + 5], i6 = csr[s + 6], i7 = csr[s + 7];
    unsigned int u0 = h2[(size_t)i0 * 64 + lane];
    unsigned int u1 = h2[(size_t)i1 * 64 + lane];
    unsigned int u2 = h2[(size_t)i2 * 64 + lane];
    unsigned int u3 = h2[(size_t)i3 * 64 + lane];
    unsigned int u4 = h2[(size_t)i4 * 64 + lane];
    unsigned int u5 = h2[(size_t)i5 * 64 + lane];
    unsigned int u6 = h2[(size_t)i6 * 64 + lane];
    unsigned int u7 = h2[(size_t)i7 * 64 + lane];
    ax += (bf_lo(u0) + bf_lo(u1)) + (bf_lo(u2) + bf_lo(u3)) +
          (bf_lo(u4) + bf_lo(u5)) + (bf_lo(u6) + bf_lo(u7));
    ay += (bf_hi(u0) + bf_hi(u1)) + (bf_hi(u2) + bf_hi(u3)) +
          (bf_hi(u4) + bf_hi(u5)) + (bf_hi(u6) + bf_hi(u7));
  }
  for (; s < end; ++s) {
    unsigned int u = h2[(size_t)csr[s] * 64 + lane];
    ax += bf_lo(u); ay += bf_hi(u);
  }
  float di = dinv[node];
  float2 bb = ((const float2*)bias)[lane];
  float2 r;
  r.x = fmaf(ax, di, bb.x);
  r.y = fmaf(ay, di, bb.y);
  ((float2*)out)[(size_t)node * 64 + lane] = r;
}

extern "C" void kernel_launch(void* const* d_in, const int* in_sizes, int n_in,
                              void* d_out, int out_size, void* d_ws, size_t ws_size,
                              hipStream_t stream) {
  const float* x = (const float*)d_in[0];
  const int* ei = (const int*)d_in[1];   // harness delivers integers as int32
  const float* Wm = (const float*)d_in[2];
  const float* bias = (const float*)d_in[3];
  float* out = (float*)d_out;

  int N = in_sizes[0] / 128;
  int E = in_sizes[1] / 2;
  int NB64 = (N + 63) >> 6;
  int NB128 = (N + 127) >> 7;

  int nb_n = (N + 255) / 256;
  int nb_e4 = ((E + 3) / 4 + 255) / 256;

  // ---- v13: dinv[N] | bcursor[1024] | pairs[NB128*CAP] | h[N*128 bf16] ----
  size_t off_bc = ((size_t)N * 4 + 255) & ~(size_t)255;
  size_t off_pairs = off_bc + 4096;
  size_t off_h = (off_pairs + (size_t)NB128 * CAP * 4 + 255) & ~(size_t)255;
  size_t need13 = off_h + (size_t)N * 256;

  if (ws_size >= need13 && N <= (1 << 17) && NB128 <= 1024) {
    char* p = (char*)d_ws;
    float* dinv = (float*)p;
    int* bcursor = (int*)(p + off_bc);
    int* pairs = (int*)(p + off_pairs);
    unsigned short* h = (unsigned short*)(p + off_h);

    k_zero<<<4, 256, 0, stream>>>(bcursor, 1024);
    k_scatter<<<(E + SC_T - 1) / SC_T, 512, 0, stream>>>(ei, bcursor, pairs, E, NB128);
    k_deg<<<NB128, 256, 0, stream>>>(pairs, bcursor, dinv, N);
    k_gemm_h<<<NB64, 256, 0, stream>>>(x, Wm, dinv, h, N);
    k_sort_agg<<<NB128, 512, 0, stream>>>(pairs, bcursor, (const uint4*)h, bias, out, N);
    return;
  }

  // ---- round-3 CSR fallback ----
  char* p = (char*)d_ws;
  int* cnt = (int*)p;        p += (size_t)N * 4;
  int* offs = (int*)p;       p += (size_t)N * 4;
  int* offs2 = (int*)p;      p += (size_t)N * 4;
  float* dinv = (float*)p;   p += (size_t)N * 4;
  int* bsums = (int*)p;      p += 1024;
  int* csr = (int*)p;        p += (size_t)E * 4;
  unsigned short* h = (unsigned short*)p;

  int nb_scan = (N + SCAN_E - 1) / SCAN_E;

  k_init<<<nb_n, 256, 0, stream>>>(cnt, N);
  k_count4<<<nb_e4, 256, 0, stream>>>(ei, cnt, E);
  k_scan_local<<<nb_scan, SCAN_T, 0, stream>>>(cnt, offs, bsums, N);
  k_scan_bsums<<<1, SCAN_T, 0, stream>>>(bsums, nb_scan);
  k_scan_finish<<<nb_n, 256, 0, stream>>>(offs, bsums, cnt, offs2, dinv, N);
  k_fill4<<<nb_e4, 256, 0, stream>>>(ei, offs2, csr, E);
  k_gemm_h<<<NB64, 256, 0, stream>>>(x, Wm, dinv, h, N);
  k_agg_bias_csr<<<(N + WPB - 1) / WPB, 256, 0, stream>>>(
      (const unsigned int*)h, dinv, offs, cnt, csr, bias, out, N);
}

// Round 9
// 204.290 us; speedup vs baseline: 6.7403x; 1.0053x over previous
//
#include <hip/hip_runtime.h>

// GCNConv: out = A_hat @ x @ W + b, A_hat = D^-1/2 (A + I) D^-1/2
// v14: 128-node buckets. k_zero -> k_scatter (2-pass LDS histogram) ->
// k_gemm_hd (FUSED: per-bucket LDS hist from pairs -> dinv local; 128-row
// W-tile reuse; bf16 MFMA h' = dinv*xW) -> k_sort_agg (slim LDS: no pb[]
// copy, re-read pairs for placement; LDS counting sort + 32 dynamic-claiming
// 16-lane groups gathering h rows uint4 8-deep, register acc, nt stores).
// Deletes k_deg kernel + global dinv array vs v13.

#define SCAN_T 256
#define SCAN_E 1024
#define WPB 4
#define CAP 2560      // pairs per 128-node bucket (mean 2048, +11 sigma)
#define SC_T 8192     // edges per scatter block -> 196 blocks at E=1.6M

typedef __attribute__((ext_vector_type(8))) short short8;
typedef __attribute__((ext_vector_type(4))) float f32x4;

__device__ __forceinline__ unsigned short f2bf(float f) {
  unsigned int u = __float_as_uint(f);
  u += 0x7FFFu + ((u >> 16) & 1u);   // RNE
  return (unsigned short)(u >> 16);
}
__device__ __forceinline__ float bf_lo(unsigned int u) { return __uint_as_float(u << 16); }
__device__ __forceinline__ float bf_hi(unsigned int u) { return __uint_as_float(u & 0xFFFF0000u); }

// ======================= v14 primary path =======================

__global__ void k_zero(int* __restrict__ p, int m) {
  int i = blockIdx.x * blockDim.x + threadIdx.x;
  if (i < m) p[i] = 0;
}

// Bucket-scatter: pairs[b*CAP + slot] = (dst&127)<<17 | src. bucket = dst>>7.
__global__ void __launch_bounds__(512) k_scatter(
    const int* __restrict__ ei, int* __restrict__ bcursor,
    int* __restrict__ pairs, int E, int B) {
  __shared__ int hist[1024];
  int t = threadIdx.x;
  for (int b = t; b < B; b += 512) hist[b] = 0;
  __syncthreads();
  int e0 = blockIdx.x * SC_T;
  int eend = min(e0 + SC_T, E);
  for (int e = e0 + t * 4; e < eend; e += 2048) {
    if (e + 3 < eend) {
      int4 d = *(const int4*)(ei + E + e);
      atomicAdd(&hist[((unsigned)d.x) >> 7], 1);
      atomicAdd(&hist[((unsigned)d.y) >> 7], 1);
      atomicAdd(&hist[((unsigned)d.z) >> 7], 1);
      atomicAdd(&hist[((unsigned)d.w) >> 7], 1);
    } else {
      for (int q = e; q < eend; ++q) atomicAdd(&hist[((unsigned)ei[E + q]) >> 7], 1);
    }
  }
  __syncthreads();
  for (int b = t; b < B; b += 512) {
    int c = hist[b];
    hist[b] = c ? atomicAdd(&bcursor[b], c) : 0;  // base within bucket
  }
  __syncthreads();
  for (int e = e0 + t * 4; e < eend; e += 2048) {
    if (e + 3 < eend) {
      int4 s = *(const int4*)(ei + e);
      int4 d = *(const int4*)(ei + E + e);
      int b0 = ((unsigned)d.x) >> 7; int p0 = atomicAdd(&hist[b0], 1);
      if (p0 < CAP) pairs[(size_t)b0 * CAP + p0] = ((d.x & 127) << 17) | s.x;
      int b1 = ((unsigned)d.y) >> 7; int p1 = atomicAdd(&hist[b1], 1);
      if (p1 < CAP) pairs[(size_t)b1 * CAP + p1] = ((d.y & 127) << 17) | s.y;
      int b2 = ((unsigned)d.z) >> 7; int p2 = atomicAdd(&hist[b2], 1);
      if (p2 < CAP) pairs[(size_t)b2 * CAP + p2] = ((d.z & 127) << 17) | s.z;
      int b3 = ((unsigned)d.w) >> 7; int p3 = atomicAdd(&hist[b3], 1);
      if (p3 < CAP) pairs[(size_t)b3 * CAP + p3] = ((d.w & 127) << 17) | s.w;
    } else {
      for (int q = e; q < eend; ++q) {
        int dst = ei[E + q], src = ei[q];
        int b0 = ((unsigned)dst) >> 7; int p0 = atomicAdd(&hist[b0], 1);
        if (p0 < CAP) pairs[(size_t)b0 * CAP + p0] = ((dst & 127) << 17) | src;
      }
    }
  }
}

// Fused deg + GEMM. Block b == bucket b == rows b*128..b*128+127.
// Phase A: LDS hist of bucket pairs (-> dinv local) || stage W^T bf16.
// Phase B: bf16 MFMA h' = dinv * (x @ W), two 64-row halves reuse W tile.
__global__ void __launch_bounds__(256) k_gemm_hd(
    const float* __restrict__ x, const float* __restrict__ W,
    const int* __restrict__ pairs, const int* __restrict__ bcursor,
    unsigned short* __restrict__ h, int n) {
  __shared__ alignas(16) unsigned short Wt[128][136];
  __shared__ int hist[128];
  int t = threadIdx.x;
  int b = blockIdx.x;
  if (t < 128) hist[t] = 0;
  __syncthreads();
  int cnt = min(bcursor[b], CAP);
  const int* __restrict__ gp = pairs + (size_t)b * CAP;
  for (int i = t; i < cnt; i += 256) atomicAdd(&hist[gp[i] >> 17], 1);
  // stage W^T as bf16: read W[kg*4+i][nn] coalesced, write 4 k-consecutive
#pragma unroll
  for (int p = 0; p < 16; ++p) {
    int task = p * 256 + t;
    int kg = task >> 7, nn = task & 127;
    float w0 = W[(kg * 4 + 0) * 128 + nn];
    float w1 = W[(kg * 4 + 1) * 128 + nn];
    float w2 = W[(kg * 4 + 2) * 128 + nn];
    float w3 = W[(kg * 4 + 3) * 128 + nn];
    ushort4 u;
    u.x = f2bf(w0); u.y = f2bf(w1); u.z = f2bf(w2); u.w = f2bf(w3);
    *(ushort4*)&Wt[nn][kg * 4] = u;
  }
  __syncthreads();
  int w = t >> 6, lane = t & 63;
  int q = lane >> 4, m = lane & 15;
#pragma unroll
  for (int rep = 0; rep < 2; ++rep) {
    int lbase = rep * 64 + w * 16;          // local row base within bucket
    int r0 = (b << 7) + lbase;
    f32x4 acc[8];
#pragma unroll
    for (int nt = 0; nt < 8; ++nt) acc[nt] = (f32x4){0.f, 0.f, 0.f, 0.f};
    float dscale[4];
#pragma unroll
    for (int rg = 0; rg < 4; ++rg)
      dscale[rg] = rsqrtf((float)hist[lbase + q * 4 + rg] + 1.0f);
#pragma unroll
    for (int ks = 0; ks < 4; ++ks) {
      int row = r0 + m;
      row = row < n ? row : n - 1;
      const float* xp = x + (size_t)row * 128 + ks * 32 + q * 8;
      float4 a0 = *(const float4*)xp;
      float4 a1 = *(const float4*)(xp + 4);
      short8 af;
      af[0] = (short)f2bf(a0.x); af[1] = (short)f2bf(a0.y);
      af[2] = (short)f2bf(a0.z); af[3] = (short)f2bf(a0.w);
      af[4] = (short)f2bf(a1.x); af[5] = (short)f2bf(a1.y);
      af[6] = (short)f2bf(a1.z); af[7] = (short)f2bf(a1.w);
#pragma unroll
      for (int nt = 0; nt < 8; ++nt) {
        short8 bf = *(const short8*)&Wt[nt * 16 + m][ks * 32 + q * 8];
        acc[nt] = __builtin_amdgcn_mfma_f32_16x16x32_bf16(af, bf, acc[nt], 0, 0, 0);
      }
    }
#pragma unroll
    for (int nt = 0; nt < 8; ++nt)
#pragma unroll
      for (int rg = 0; rg < 4; ++rg) {
        int r = r0 + q * 4 + rg;
        if (r < n) h[(size_t)r * 128 + nt * 16 + m] = f2bf(acc[nt][rg] * dscale[rg]);
      }
  }
}

// Fused sort + aggregate for a 128-node bucket, 512 threads. Slim LDS:
// no pb[] copy (placement pass re-reads pairs from global, L2-hot).
// Phase 2: 32 16-lane groups dynamically claim nodes; gather h[src] rows
// (uint4, 8-deep unroll, register accumulate); out = dinv*a + bias, nt store.
__global__ void __launch_bounds__(512) k_sort_agg(
    const int* __restrict__ pairs, const int* __restrict__ bcursor,
    const uint4* __restrict__ h4, const float* __restrict__ bias,
    float* __restrict__ out, int n) {
  __shared__ int sorted[CAP];
  __shared__ int hist[128], base_[128], cur[128];
  __shared__ int nextn;
  int t = threadIdx.x;
  int b = blockIdx.x;
  if (t < 128) { hist[t] = 0; cur[t] = 0; }
  if (t == 0) nextn = 0;
  __syncthreads();
  int cnt = min(bcursor[b], CAP);
  const int* __restrict__ gp = pairs + (size_t)b * CAP;
  for (int i = t; i < cnt; i += 512) atomicAdd(&hist[gp[i] >> 17], 1);
  __syncthreads();
  // exclusive scan of hist[128] via LDS Hillis-Steele
  if (t < 128) base_[t] = hist[t];
  __syncthreads();
#pragma unroll
  for (int d = 1; d < 128; d <<= 1) {
    int v = (t < 128 && t >= d) ? base_[t - d] : 0;
    __syncthreads();
    if (t < 128) base_[t] += v;
    __syncthreads();
  }
  if (t < 128) base_[t] -= hist[t];
  __syncthreads();
  for (int i = t; i < cnt; i += 512) {
    int p = gp[i];
    int d = p >> 17;
    int pos = base_[d] + atomicAdd(&cur[d], 1);
    sorted[pos] = p & 0x1FFFF;
  }
  __syncthreads();

  // ---- phase 2: gather-aggregate with dynamic node claiming ----
  int lane = t & 63;
  int ln = lane & 15;
  int nbase = b << 7;
  for (;;) {
    int row = 0;
    if (ln == 0) row = atomicAdd(&nextn, 1);
    row = __shfl(row, lane & 48, 64);   // broadcast to the 16-lane group
    if (row >= 128) break;
    int node = nbase + row;
    bool act = node < n;
    uint4 sp = make_uint4(0u, 0u, 0u, 0u);
    if (act) sp = h4[(size_t)node * 16 + ln];  // self term
    float a[8];
    a[0] = bf_lo(sp.x); a[1] = bf_hi(sp.x);
    a[2] = bf_lo(sp.y); a[3] = bf_hi(sp.y);
    a[4] = bf_lo(sp.z); a[5] = bf_hi(sp.z);
    a[6] = bf_lo(sp.w); a[7] = bf_hi(sp.w);
    int s = base_[row];
    int cd = hist[row];
    int end = s + cd;
    for (; s + 8 <= end; s += 8) {
      uint4 u[8];
#pragma unroll
      for (int k = 0; k < 8; ++k) {
        int idx = sorted[s + k];
        u[k] = h4[(size_t)idx * 16 + ln];
      }
#pragma unroll
      for (int k = 0; k < 8; ++k) {
        a[0] += bf_lo(u[k].x); a[1] += bf_hi(u[k].x);
        a[2] += bf_lo(u[k].y); a[3] += bf_hi(u[k].y);
        a[4] += bf_lo(u[k].z); a[5] += bf_hi(u[k].z);
        a[6] += bf_lo(u[k].w); a[7] += bf_hi(u[k].w);
      }
    }
    for (; s + 4 <= end; s += 4) {
      uint4 u[4];
#pragma unroll
      for (int k = 0; k < 4; ++k) {
        int idx = sorted[s + k];
        u[k] = h4[(size_t)idx * 16 + ln];
      }
#pragma unroll
      for (int k = 0; k < 4; ++k) {
        a[0] += bf_lo(u[k].x); a[1] += bf_hi(u[k].x);
        a[2] += bf_lo(u[k].y); a[3] += bf_hi(u[k].y);
        a[4] += bf_lo(u[k].z); a[5] += bf_hi(u[k].z);
        a[6] += bf_lo(u[k].w); a[7] += bf_hi(u[k].w);
      }
    }
    for (; s < end; ++s) {
      int idx = sorted[s];
      uint4 u = h4[(size_t)idx * 16 + ln];
      a[0] += bf_lo(u.x); a[1] += bf_hi(u.x);
      a[2] += bf_lo(u.y); a[3] += bf_hi(u.y);
      a[4] += bf_lo(u.z); a[5] += bf_hi(u.z);
      a[6] += bf_lo(u.w); a[7] += bf_hi(u.w);
    }
    if (act) {
      float di = rsqrtf((float)cd + 1.0f);
      float4 b0 = ((const float4*)bias)[2 * ln];
      float4 b1 = ((const float4*)bias)[2 * ln + 1];
      f32x4 r0, r1;
      r0[0] = fmaf(a[0], di, b0.x); r0[1] = fmaf(a[1], di, b0.y);
      r0[2] = fmaf(a[2], di, b0.z); r0[3] = fmaf(a[3], di, b0.w);
      r1[0] = fmaf(a[4], di, b1.x); r1[1] = fmaf(a[5], di, b1.y);
      r1[2] = fmaf(a[6], di, b1.z); r1[3] = fmaf(a[7], di, b1.w);
      f32x4* op = (f32x4*)(out + (size_t)node * 128 + ln * 8);
      __builtin_nontemporal_store(r0, op);
      __builtin_nontemporal_store(r1, op + 1);
    }
  }
}

// ======================= round-3 CSR fallback =======================

__global__ void k_init(int* __restrict__ cnt, int n) {
  int i = blockIdx.x * blockDim.x + threadIdx.x;
  if (i < n) cnt[i] = 0;
}

__global__ void k_count4(const int* __restrict__ ei, int* __restrict__ cnt, int E) {
  int i = blockIdx.x * blockDim.x + threadIdx.x;
  int e = i * 4;
  if (e + 3 < E) {
    int4 d = *(const int4*)(ei + E + e);
    atomicAdd(&cnt[d.x], 1); atomicAdd(&cnt[d.y], 1);
    atomicAdd(&cnt[d.z], 1); atomicAdd(&cnt[d.w], 1);
  } else {
    for (; e < E; ++e) atomicAdd(&cnt[ei[E + e]], 1);
  }
}

__global__ void k_scan_local(const int* __restrict__ cnt, int* __restrict__ offs,
                             int* __restrict__ bsums, int n) {
  __shared__ int sh[SCAN_T];
  int t = threadIdx.x;
  int base = blockIdx.x * SCAN_E + t * 4;
  int v0 = 0, v1 = 0, v2 = 0, v3 = 0;
  if (base + 0 < n) v0 = cnt[base + 0];
  if (base + 1 < n) v1 = cnt[base + 1];
  if (base + 2 < n) v2 = cnt[base + 2];
  if (base + 3 < n) v3 = cnt[base + 3];
  int sum = v0 + v1 + v2 + v3;
  sh[t] = sum;
  __syncthreads();
  for (int d = 1; d < SCAN_T; d <<= 1) {
    int xv = (t >= d) ? sh[t - d] : 0;
    __syncthreads();
    sh[t] += xv;
    __syncthreads();
  }
  int run = sh[t] - sum;
  if (base + 0 < n) offs[base + 0] = run; run += v0;
  if (base + 1 < n) offs[base + 1] = run; run += v1;
  if (base + 2 < n) offs[base + 2] = run; run += v2;
  if (base + 3 < n) offs[base + 3] = run;
  if (t == SCAN_T - 1) bsums[blockIdx.x] = sh[t];
}

__global__ void k_scan_bsums(int* __restrict__ bsums, int nb) {
  __shared__ int sh[SCAN_T];
  int t = threadIdx.x;
  int v = (t < nb) ? bsums[t] : 0;
  sh[t] = v;
  __syncthreads();
  for (int d = 1; d < SCAN_T; d <<= 1) {
    int xv = (t >= d) ? sh[t - d] : 0;
    __syncthreads();
    sh[t] += xv;
    __syncthreads();
  }
  if (t < nb) bsums[t] = sh[t] - v;
}

__global__ void k_scan_finish(int* __restrict__ offs, const int* __restrict__ bsums,
                              const int* __restrict__ cnt, int* __restrict__ offs2,
                              float* __restrict__ dinv, int n) {
  int i = blockIdx.x * blockDim.x + threadIdx.x;
  if (i < n) {
    int o = offs[i] + bsums[i / SCAN_E];
    offs[i] = o;
    offs2[i] = o;
    dinv[i] = rsqrtf((float)cnt[i] + 1.0f);
  }
}

__global__ void k_fill4(const int* __restrict__ ei, int* __restrict__ offs2,
                        int* __restrict__ csr, int E) {
  int i = blockIdx.x * blockDim.x + threadIdx.x;
  int e = i * 4;
  if (e + 3 < E) {
    int4 s = *(const int4*)(ei + e);
    int4 d = *(const int4*)(ei + E + e);
    csr[atomicAdd(&offs2[d.x], 1)] = s.x;
    csr[atomicAdd(&offs2[d.y], 1)] = s.y;
    csr[atomicAdd(&offs2[d.z], 1)] = s.z;
    csr[atomicAdd(&offs2[d.w], 1)] = s.w;
  } else {
    for (; e < E; ++e) csr[atomicAdd(&offs2[ei[E + e]], 1)] = ei[e];
  }
}

__global__ void __launch_bounds__(256) k_gemm_h(
    const float* __restrict__ x, const float* __restrict__ W,
    const float* __restrict__ dinv, unsigned short* __restrict__ h, int n) {
  __shared__ alignas(16) unsigned short Wt[128][136];
  int t = threadIdx.x;
#pragma unroll
  for (int p = 0; p < 16; ++p) {
    int task = p * 256 + t;
    int kg = task >> 7, nn = task & 127;
    float w0 = W[(kg * 4 + 0) * 128 + nn];
    float w1 = W[(kg * 4 + 1) * 128 + nn];
    float w2 = W[(kg * 4 + 2) * 128 + nn];
    float w3 = W[(kg * 4 + 3) * 128 + nn];
    ushort4 u;
    u.x = f2bf(w0); u.y = f2bf(w1); u.z = f2bf(w2); u.w = f2bf(w3);
    *(ushort4*)&Wt[nn][kg * 4] = u;
  }
  __syncthreads();
  int w = t >> 6, lane = t & 63;
  int q = lane >> 4, m = lane & 15;
  int r0 = blockIdx.x * 64 + w * 16;
  f32x4 acc[8];
#pragma unroll
  for (int nt = 0; nt < 8; ++nt) acc[nt] = (f32x4){0.f, 0.f, 0.f, 0.f};
  float dscale[4];
#pragma unroll
  for (int rg = 0; rg < 4; ++rg) {
    int r = r0 + q * 4 + rg;
    dscale[rg] = dinv[r < n ? r : n - 1];
  }
#pragma unroll
  for (int ks = 0; ks < 4; ++ks) {
    int row = r0 + m;
    row = row < n ? row : n - 1;
    const float* xp = x + (size_t)row * 128 + ks * 32 + q * 8;
    float4 a0 = *(const float4*)xp;
    float4 a1 = *(const float4*)(xp + 4);
    short8 af;
    af[0] = (short)f2bf(a0.x); af[1] = (short)f2bf(a0.y);
    af[2] = (short)f2bf(a0.z); af[3] = (short)f2bf(a0.w);
    af[4] = (short)f2bf(a1.x); af[5] = (short)f2bf(a1.y);
    af[6] = (short)f2bf(a1.z); af[7] = (short)f2bf(a1.w);
#pragma unroll
    for (int nt = 0; nt < 8; ++nt) {
      short8 bf = *(const short8*)&Wt[nt * 16 + m][ks * 32 + q * 8];
      acc[nt] = __builtin_amdgcn_mfma_f32_16x16x32_bf16(af, bf, acc[nt], 0, 0, 0);
    }
  }
#pragma unroll
  for (int nt = 0; nt < 8; ++nt)
#pragma unroll
    for (int rg = 0; rg < 4; ++rg) {
      int r = r0 + q * 4 + rg;
      if (r < n) h[(size_t)r * 128 + nt * 16 + m] = f2bf(acc[nt][rg] * dscale[rg]);
    }
}

__global__ void __launch_bounds__(256) k_agg_bias_csr(
    const unsigned int* __restrict__ h2, const float* __restrict__ dinv,
    const int* __restrict__ offs, const int* __restrict__ cnt,
    const int* __restrict__ csr, const float* __restrict__ bias,
    float* __restrict__ out, int n) {
  int node = blockIdx.x * WPB + (threadIdx.x >> 6);
  int lane = threadIdx.x & 63;
  if (node >= n) return;
  unsigned int sp = h2[(size_t)node * 64 + lane];
  float ax = bf_lo(sp), ay = bf_hi(sp);
  int s = offs[node];
  int end = s + cnt[node];
  for (; s + 8 <= end; s += 8) {
    int i0 = csr[s + 0], i1 = csr[s + 1], i2 = csr[s + 2], i3 = csr[s + 3];
    int i4 = csr[s + 4], i5 = csr[s + 5], i6 = csr[s + 6], i7 = csr[s + 7];
    unsigned int u0 = h2[(size_t)i0 * 64 + lane];
    unsigned int u1 = h2[(size_t)i1 * 64 + lane];
    unsigned int u2 = h2[(size_t)i2 * 64 + lane];
    unsigned int u3 = h2[(size_t)i3 * 64 + lane];
    unsigned int u4 = h2[(size_t)i4 * 64 + lane];
    unsigned int u5 = h2[(size_t)i5 * 64 + lane];
    unsigned int u6 = h2[(size_t)i6 * 64 + lane];
    unsigned int u7 = h2[(size_t)i7 * 64 + lane];
    ax += (bf_lo(u0) + bf_lo(u1)) + (bf_lo(u2) + bf_lo(u3)) +
          (bf_lo(u4) + bf_lo(u5)) + (bf_lo(u6) + bf_lo(u7));
    ay += (bf_hi(u0) + bf_hi(u1)) + (bf_hi(u2) + bf_hi(u3)) +
          (bf_hi(u4) + bf_hi(u5)) + (bf_hi(u6) + bf_hi(u7));
  }
  for (; s < end; ++s) {
    unsigned int u = h2[(size_t)csr[s] * 64 + lane];
    ax += bf_lo(u); ay += bf_hi(u);
  }
  float di = dinv[node];
  float2 bb = ((const float2*)bias)[lane];
  float2 r;
  r.x = fmaf(ax, di, bb.x);
  r.y = fmaf(ay, di, bb.y);
  ((float2*)out)[(size_t)node * 64 + lane] = r;
}

extern "C" void kernel_launch(void* const* d_in, const int* in_sizes, int n_in,
                              void* d_out, int out_size, void* d_ws, size_t ws_size,
                              hipStream_t stream) {
  const float* x = (const float*)d_in[0];
  const int* ei = (const int*)d_in[1];   // harness delivers integers as int32
  const float* Wm = (const float*)d_in[2];
  const float* bias = (const float*)d_in[3];
  float* out = (float*)d_out;

  int N = in_sizes[0] / 128;
  int E = in_sizes[1] / 2;
  int NB64 = (N + 63) >> 6;
  int NB128 = (N + 127) >> 7;

  int nb_n = (N + 255) / 256;
  int nb_e4 = ((E + 3) / 4 + 255) / 256;

  // ---- v14: bcursor[1024] | pairs[NB128*CAP] | h[N*128 bf16] ----
  size_t off_pairs = 4096;
  size_t off_h = (off_pairs + (size_t)NB128 * CAP * 4 + 255) & ~(size_t)255;
  size_t need14 = off_h + (size_t)N * 256;

  if (ws_size >= need14 && N <= (1 << 17) && NB128 <= 1024) {
    char* p = (char*)d_ws;
    int* bcursor = (int*)p;
    int* pairs = (int*)(p + off_pairs);
    unsigned short* h = (unsigned short*)(p + off_h);

    k_zero<<<4, 256, 0, stream>>>(bcursor, 1024);
    k_scatter<<<(E + SC_T - 1) / SC_T, 512, 0, stream>>>(ei, bcursor, pairs, E, NB128);
    k_gemm_hd<<<NB128, 256, 0, stream>>>(x, Wm, pairs, bcursor, h, N);
    k_sort_agg<<<NB128, 512, 0, stream>>>(pairs, bcursor, (const uint4*)h, bias, out, N);
    return;
  }

  // ---- round-3 CSR fallback ----
  char* p = (char*)d_ws;
  int* cnt = (int*)p;        p += (size_t)N * 4;
  int* offs = (int*)p;       p += (size_t)N * 4;
  int* offs2 = (int*)p;      p += (size_t)N * 4;
  float* dinv = (float*)p;   p += (size_t)N * 4;
  int* bsums = (int*)p;      p += 1024;
  int* csr = (int*)p;        p += (size_t)E * 4;
  unsigned short* h = (unsigned short*)p;

  int nb_scan = (N + SCAN_E - 1) / SCAN_E;

  k_init<<<nb_n, 256, 0, stream>>>(cnt, N);
  k_count4<<<nb_e4, 256, 0, stream>>>(ei, cnt, E);
  k_scan_local<<<nb_scan, SCAN_T, 0, stream>>>(cnt, offs, bsums, N);
  k_scan_bsums<<<1, SCAN_T, 0, stream>>>(bsums, nb_scan);
  k_scan_finish<<<nb_n, 256, 0, stream>>>(offs, bsums, cnt, offs2, dinv, N);
  k_fill4<<<nb_e4, 256, 0, stream>>>(ei, offs2, csr, E);
  k_gemm_h<<<NB64, 256, 0, stream>>>(x, Wm, dinv, h, N);
  k_agg_bias_csr<<<(N + WPB - 1) / WPB, 256, 0, stream>>>(
      (const unsigned int*)h, dinv, offs, cnt, csr, bias, out, N);
}